// Round 1
// baseline (264.843 us; speedup 1.0000x reference)
//
#include <hip/hip_runtime.h>
#include <hip/hip_bf16.h>
#include <cstdint>
#include <cstddef>

// ---------- types ----------
using bf16x8 = __attribute__((ext_vector_type(8))) __bf16;
using f32x4  = __attribute__((ext_vector_type(4))) float;

__device__ __forceinline__ float b2f(unsigned short u) {
  union { unsigned u; float f; } x; x.u = ((unsigned)u) << 16; return x.f;
}
__device__ __forceinline__ unsigned short f2b(float f) {
  union { float f; unsigned u; } x; x.f = f;
  unsigned r = x.u + 0x7fffu + ((x.u >> 16) & 1u);
  return (unsigned short)(r >> 16);
}

// async global->LDS, 16B per lane. dst must be wave-uniform base (HW adds lane*16).
__device__ __forceinline__ void gload_lds16(const void* g, void* l) {
  __builtin_amdgcn_global_load_lds(
      (const __attribute__((address_space(1))) void*)g,
      (__attribute__((address_space(3))) void*)l, 16, 0, 0);
}

__device__ __forceinline__ bf16x8 ldfrag(const unsigned short* p) {
  return *reinterpret_cast<const bf16x8*>(p);
}

// ---------- prep kernels ----------
__global__ __launch_bounds__(256) void cast_kernel(const float* __restrict__ s,
                                                   unsigned short* __restrict__ d, int n4) {
  int i = blockIdx.x * 256 + threadIdx.x;
  if (i >= n4) return;
  float4 v = reinterpret_cast<const float4*>(s)[i];
  ushort4 o;
  o.x = f2b(v.x); o.y = f2b(v.y); o.z = f2b(v.z); o.w = f2b(v.w);
  reinterpret_cast<ushort4*>(d)[i] = o;
}

__global__ __launch_bounds__(256) void sincos_kernel(float* __restrict__ st,
                                                     float* __restrict__ ct, int total) {
  int i = blockIdx.x * 256 + threadIdx.x;
  if (i >= total) return;
  int n = i >> 5, j = i & 31;
  float inv = powf(10000.0f, -(float)j * (1.0f / 32.0f));
  float ang = (float)n * inv;
  st[i] = sinf(ang);
  ct[i] = cosf(ang);
}

// ---------- GEMM: C[M][N] = A[M][K] * B[N][K]^T (+bias), bf16 in, f32 acc ----------
// m97 structure: 128x128 tile, BK=32, 4 waves (2x2), 4x4 16x16 frags per wave.
template <int OUTF32>
__global__ __launch_bounds__(256) void gemm_bt(const unsigned short* __restrict__ A,
                                               const unsigned short* __restrict__ B,
                                               void* __restrict__ C,
                                               const float* __restrict__ bias,
                                               int M, int N, int K) {
  __shared__ __align__(16) unsigned short As[128 * 32];
  __shared__ __align__(16) unsigned short Bs[128 * 32];
  const int tid = threadIdx.x;
  const int lane = tid & 63, wave = tid >> 6;
  const int wr = wave >> 1, wc = wave & 1;
  const int bm = blockIdx.y * 128, bn = blockIdx.x * 128;
  const int lr = lane & 15, lk = lane >> 4;
  f32x4 acc[4][4] = {};

  for (int k0 = 0; k0 < K; k0 += 32) {
#pragma unroll
    for (int i = 0; i < 2; ++i) {
      int idx = i * 256 + tid;
      int row = idx >> 2, c8 = (idx & 3) * 8;  // 4 chunks of 16B per 32-col row
      gload_lds16(A + (size_t)(bm + row) * K + k0 + c8, &As[(i * 256 + wave * 64) * 8]);
      gload_lds16(B + (size_t)(bn + row) * K + k0 + c8, &Bs[(i * 256 + wave * 64) * 8]);
    }
    __syncthreads();
    bf16x8 af[4], bfr[4];
#pragma unroll
    for (int mi = 0; mi < 4; ++mi)
      af[mi] = ldfrag(&As[(wr * 64 + mi * 16 + lr) * 32 + lk * 8]);
#pragma unroll
    for (int ni = 0; ni < 4; ++ni)
      bfr[ni] = ldfrag(&Bs[(wc * 64 + ni * 16 + lr) * 32 + lk * 8]);
#pragma unroll
    for (int mi = 0; mi < 4; ++mi)
#pragma unroll
      for (int ni = 0; ni < 4; ++ni)
        acc[mi][ni] = __builtin_amdgcn_mfma_f32_16x16x32_bf16(af[mi], bfr[ni], acc[mi][ni], 0, 0, 0);
    __syncthreads();
  }

#pragma unroll
  for (int mi = 0; mi < 4; ++mi) {
#pragma unroll
    for (int ni = 0; ni < 4; ++ni) {
      int col = bn + wc * 64 + ni * 16 + lr;
      float bv = bias ? bias[col] : 0.0f;
#pragma unroll
      for (int r = 0; r < 4; ++r) {
        int row = bm + wr * 64 + mi * 16 + lk * 4 + r;
        float v = acc[mi][ni][r] + bv;
        if (OUTF32)
          reinterpret_cast<float*>(C)[(size_t)row * N + col] = v;
        else
          reinterpret_cast<unsigned short*>(C)[(size_t)row * N + col] = f2b(v);
      }
    }
  }
}

// ---------- RoPE: qkv[B*N][3072] -> Qo/Ko [B*16][N][64] (q pre-scaled by 1/8) ----------
__global__ __launch_bounds__(256) void rope_kernel(const unsigned short* __restrict__ qkv,
                                                   const float* __restrict__ st,
                                                   const float* __restrict__ ct,
                                                   unsigned short* __restrict__ Qo,
                                                   unsigned short* __restrict__ Ko, int N) {
  const int lane = threadIdx.x & 63;
  const int gw = (int)((blockIdx.x * 256 + threadIdx.x) >> 6);
  const int total = 2 * 2 * N * 16;
  if (gw >= total) return;
  const int which = gw / (2 * N * 16);  // 0=q, 1=k
  int rem = gw - which * (2 * N * 16);
  const int b = rem / (N * 16);
  rem -= b * (N * 16);
  const int n = rem >> 4, h = rem & 15;
  const int d = lane;
  float v = b2f(qkv[((size_t)(b * N + n)) * 3072 + which * 1024 + h * 64 + d]);
  const int j = d & 31;
  float c = ct[n * 32 + j], s = st[n * 32 + j];
  int partner = (d < 32) ? (2 * d + 1) : (2 * (d - 32));
  float pv = __shfl(v, partner, 64);
  float res = (d < 32) ? (v * c - pv * s) : (v * c + pv * s);
  if (which == 0) res *= 0.125f;  // fold 1/sqrt(D) into q
  unsigned short* dst = which ? Ko : Qo;
  dst[(((size_t)(b * 16 + h)) * N + n) * 64 + d] = f2b(res);
}

// ---------- V transpose: qkv v-part [n][d] -> Vt[bh][d][n] ----------
__global__ __launch_bounds__(256) void vtrans_kernel(const unsigned short* __restrict__ qkv,
                                                     unsigned short* __restrict__ Vt, int N) {
  __shared__ __align__(16) unsigned short T[64][80];  // pad to 80 shorts (160B rows)
  const int bh = blockIdx.y, b = bh >> 4, h = bh & 15;
  const int n0 = blockIdx.x * 64;
  const int tid = threadIdx.x;
#pragma unroll
  for (int i = 0; i < 2; ++i) {
    int idx = i * 256 + tid;
    int row = idx >> 3, c8 = (idx & 7) * 8;
    int4 v = *reinterpret_cast<const int4*>(
        &qkv[((size_t)(b * N + n0 + row)) * 3072 + 2048 + h * 64 + c8]);
    *reinterpret_cast<int4*>(&T[row][c8]) = v;
  }
  __syncthreads();
#pragma unroll
  for (int i = 0; i < 2; ++i) {
    int idx = i * 256 + tid;
    int d = idx >> 3, n8 = (idx & 7) * 8;
    int4 ov;
    ov.x = (int)T[n8 + 0][d] | ((int)T[n8 + 1][d] << 16);
    ov.y = (int)T[n8 + 2][d] | ((int)T[n8 + 3][d] << 16);
    ov.z = (int)T[n8 + 4][d] | ((int)T[n8 + 5][d] << 16);
    ov.w = (int)T[n8 + 6][d] | ((int)T[n8 + 7][d] << 16);
    *reinterpret_cast<int4*>(&Vt[((size_t)bh * 64 + d) * N + n0 + n8]) = ov;
  }
}

// ---------- Flash attention: Q/K [bh][N][64], Vt [bh][64][N] -> Out [B][N][1024] ----------
__global__ __launch_bounds__(256) void flash_kernel(const unsigned short* __restrict__ Q,
                                                    const unsigned short* __restrict__ Kb,
                                                    const unsigned short* __restrict__ Vt,
                                                    unsigned short* __restrict__ Out, int N) {
  __shared__ __align__(16) unsigned short Ks[64 * 64];
  __shared__ __align__(16) unsigned short Vs[64 * 64];      // [d][k]
  __shared__ __align__(16) unsigned short Ps[4][16 * 64];   // per-wave P tile
  const int tid = threadIdx.x;
  const int lane = tid & 63, wave = tid >> 6;
  const int lr = lane & 15, lk = lane >> 4;
  const int bh = blockIdx.y, q0 = blockIdx.x * 64;
  const unsigned short* Qh = Q + (size_t)bh * N * 64;
  const unsigned short* Kh = Kb + (size_t)bh * N * 64;
  const unsigned short* Vh = Vt + (size_t)bh * 64 * N;

  const bf16x8 qf0 = ldfrag(&Qh[(size_t)(q0 + wave * 16 + lr) * 64 + lk * 8]);
  const bf16x8 qf1 = ldfrag(&Qh[(size_t)(q0 + wave * 16 + lr) * 64 + 32 + lk * 8]);

  f32x4 oacc[4] = {};
  float m_run[4], l_run[4];
#pragma unroll
  for (int r = 0; r < 4; ++r) { m_run[r] = -INFINITY; l_run[r] = 0.0f; }

  for (int k0 = 0; k0 <= q0; k0 += 64) {
#pragma unroll
    for (int i = 0; i < 2; ++i) {
      int idx = i * 256 + tid;
      int row = idx >> 3, c8 = (idx & 7) * 8;  // 8 chunks of 16B per 64-col row
      gload_lds16(Kh + (size_t)(k0 + row) * 64 + c8, &Ks[(i * 256 + wave * 64) * 8]);
      gload_lds16(Vh + (size_t)row * N + k0 + c8, &Vs[(i * 256 + wave * 64) * 8]);
    }
    __syncthreads();

    // S = q @ k^T : rows = wave's 16 q-rows, cols = 64 k's
    f32x4 s[4] = {};
#pragma unroll
    for (int ni = 0; ni < 4; ++ni) {
      bf16x8 kf0 = ldfrag(&Ks[(ni * 16 + lr) * 64 + lk * 8]);
      bf16x8 kf1 = ldfrag(&Ks[(ni * 16 + lr) * 64 + 32 + lk * 8]);
      s[ni] = __builtin_amdgcn_mfma_f32_16x16x32_bf16(qf0, kf0, s[ni], 0, 0, 0);
      s[ni] = __builtin_amdgcn_mfma_f32_16x16x32_bf16(qf1, kf1, s[ni], 0, 0, 0);
    }

    if (k0 == q0) {  // diagonal tile: causal mask
#pragma unroll
      for (int ni = 0; ni < 4; ++ni)
#pragma unroll
        for (int r = 0; r < 4; ++r)
          if (k0 + ni * 16 + lr > q0 + wave * 16 + lk * 4 + r) s[ni][r] = -INFINITY;
    }

    // online softmax (rows live across the 16 lanes of each lk-group)
    float alpha[4];
#pragma unroll
    for (int r = 0; r < 4; ++r) {
      float mx = fmaxf(fmaxf(s[0][r], s[1][r]), fmaxf(s[2][r], s[3][r]));
#pragma unroll
      for (int off = 1; off < 16; off <<= 1) mx = fmaxf(mx, __shfl_xor(mx, off, 64));
      float nm = fmaxf(m_run[r], mx);
      alpha[r] = __expf(m_run[r] - nm);
      m_run[r] = nm;
    }
    float rs[4] = {0.f, 0.f, 0.f, 0.f};
#pragma unroll
    for (int ni = 0; ni < 4; ++ni)
#pragma unroll
      for (int r = 0; r < 4; ++r) {
        float p = __expf(s[ni][r] - m_run[r]);
        s[ni][r] = p;
        rs[r] += p;
      }
#pragma unroll
    for (int r = 0; r < 4; ++r) {
      float t = rs[r];
#pragma unroll
      for (int off = 1; off < 16; off <<= 1) t += __shfl_xor(t, off, 64);
      l_run[r] = l_run[r] * alpha[r] + t;
#pragma unroll
      for (int ni = 0; ni < 4; ++ni) oacc[ni][r] *= alpha[r];
    }

    // P -> LDS (bf16) so PV's A-fragment is a contiguous read (same-wave, no barrier)
    unsigned short* Pw = &Ps[wave][0];
#pragma unroll
    for (int ni = 0; ni < 4; ++ni)
#pragma unroll
      for (int r = 0; r < 4; ++r)
        Pw[(lk * 4 + r) * 64 + ni * 16 + lr] = f2b(s[ni][r]);

    // O += P @ V
#pragma unroll
    for (int c = 0; c < 2; ++c) {
      bf16x8 pf = ldfrag(&Pw[lr * 64 + c * 32 + lk * 8]);
#pragma unroll
      for (int ni = 0; ni < 4; ++ni) {
        bf16x8 vf = ldfrag(&Vs[(ni * 16 + lr) * 64 + c * 32 + lk * 8]);
        oacc[ni] = __builtin_amdgcn_mfma_f32_16x16x32_bf16(pf, vf, oacc[ni], 0, 0, 0);
      }
    }
    __syncthreads();
  }

  const int b = bh >> 4, h = bh & 15;
#pragma unroll
  for (int ni = 0; ni < 4; ++ni)
#pragma unroll
    for (int r = 0; r < 4; ++r) {
      float v = oacc[ni][r] / l_run[r];
      int n = q0 + wave * 16 + lk * 4 + r;
      Out[((size_t)(b * N + n)) * 1024 + h * 64 + ni * 16 + lr] = f2b(v);
    }
}

// ---------- launch ----------
extern "C" void kernel_launch(void* const* d_in, const int* in_sizes, int n_in,
                              void* d_out, int out_size, void* d_ws, size_t ws_size,
                              hipStream_t stream) {
  const int B = 2, N = 2048, E = 1024, C = 1024, NC = 3072;
  const int M = B * N;  // 4096

  const float* x  = (const float*)d_in[0];
  const float* Wq = (const float*)d_in[1];
  const float* bq = (const float*)d_in[2];
  const float* Wk = (const float*)d_in[3];
  const float* bk = (const float*)d_in[4];
  const float* Wv = (const float*)d_in[5];
  const float* bv = (const float*)d_in[6];
  const float* Wo = (const float*)d_in[7];
  const float* bo = (const float*)d_in[8];

  char* w = (char*)d_ws;
  size_t off = 0;
  auto alloc = [&](size_t bytes) {
    void* p = w + off;
    off += (bytes + 255) & ~(size_t)255;
    return p;
  };
  unsigned short* xb    = (unsigned short*)alloc((size_t)M * E * 2);
  unsigned short* wqkv  = (unsigned short*)alloc((size_t)NC * E * 2);
  unsigned short* wob   = (unsigned short*)alloc((size_t)E * C * 2);
  unsigned short* qkvb  = (unsigned short*)alloc((size_t)M * NC * 2);
  unsigned short* qb    = (unsigned short*)alloc((size_t)B * 16 * N * 64 * 2);
  unsigned short* kb    = (unsigned short*)alloc((size_t)B * 16 * N * 64 * 2);
  unsigned short* vt    = (unsigned short*)alloc((size_t)B * 16 * 64 * N * 2);
  unsigned short* attnb = (unsigned short*)alloc((size_t)M * C * 2);
  float* sin_t   = (float*)alloc((size_t)N * 32 * 4);
  float* cos_t   = (float*)alloc((size_t)N * 32 * 4);
  float* biasqkv = (float*)alloc((size_t)NC * 4);

  // concat qkv biases
  hipMemcpyAsync(biasqkv,         bq, C * sizeof(float), hipMemcpyDeviceToDevice, stream);
  hipMemcpyAsync(biasqkv + C,     bk, C * sizeof(float), hipMemcpyDeviceToDevice, stream);
  hipMemcpyAsync(biasqkv + 2 * C, bv, C * sizeof(float), hipMemcpyDeviceToDevice, stream);

  // casts to bf16
  int n1 = M * E / 4;
  cast_kernel<<<(n1 + 255) / 256, 256, 0, stream>>>(x, xb, n1);
  int n2 = C * E / 4;
  cast_kernel<<<(n2 + 255) / 256, 256, 0, stream>>>(Wq, wqkv, n2);
  cast_kernel<<<(n2 + 255) / 256, 256, 0, stream>>>(Wk, wqkv + (size_t)C * E, n2);
  cast_kernel<<<(n2 + 255) / 256, 256, 0, stream>>>(Wv, wqkv + (size_t)2 * C * E, n2);
  cast_kernel<<<(n2 + 255) / 256, 256, 0, stream>>>(Wo, wob, n2);

  int n3 = N * 32;
  sincos_kernel<<<(n3 + 255) / 256, 256, 0, stream>>>(sin_t, cos_t, n3);

  // QKV projection: [4096][1024] x [3072][1024]^T -> bf16 [4096][3072]
  gemm_bt<0><<<dim3(NC / 128, M / 128), 256, 0, stream>>>(xb, wqkv, qkvb, biasqkv, M, NC, E);

  // RoPE + layout to [bh][N][64]
  int nwaves = 2 * B * N * 16;
  rope_kernel<<<nwaves / 4, 256, 0, stream>>>(qkvb, sin_t, cos_t, qb, kb, N);

  // V transpose to [bh][64][N]
  vtrans_kernel<<<dim3(N / 64, B * 16), 256, 0, stream>>>(qkvb, vt, N);

  // causal flash attention -> bf16 [B*N][1024]
  flash_kernel<<<dim3(N / 64, B * 16), 256, 0, stream>>>(qb, kb, vt, attnb, N);

  // output projection: [4096][1024] x [1024][1024]^T + bo -> f32 d_out
  gemm_bt<1><<<dim3(E / 128, M / 128), 256, 0, stream>>>(attnb, wob, d_out, bo, M, E, C);
}

// Round 2
// 232.226 us; speedup vs baseline: 1.1405x; 1.1405x over previous
//
#include <hip/hip_runtime.h>
#include <hip/hip_bf16.h>
#include <cstdint>
#include <cstddef>

// ---------- types ----------
using bf16x8 = __attribute__((ext_vector_type(8))) __bf16;
using f32x4  = __attribute__((ext_vector_type(4))) float;

__device__ __forceinline__ float b2f(unsigned short u) {
  union { unsigned u; float f; } x; x.u = ((unsigned)u) << 16; return x.f;
}
__device__ __forceinline__ unsigned short f2b(float f) {
  union { float f; unsigned u; } x; x.f = f;
  unsigned r = x.u + 0x7fffu + ((x.u >> 16) & 1u);
  return (unsigned short)(r >> 16);
}

// async global->LDS, 16B per lane. dst must be wave-uniform base (HW adds lane*16).
__device__ __forceinline__ void gload_lds16(const void* g, void* l) {
  __builtin_amdgcn_global_load_lds(
      (const __attribute__((address_space(1))) void*)g,
      (__attribute__((address_space(3))) void*)l, 16, 0, 0);
}

__device__ __forceinline__ bf16x8 ldfrag(const unsigned short* p) {
  return *reinterpret_cast<const bf16x8*>(p);
}

// ---------- prep kernels ----------
__global__ __launch_bounds__(256) void cast_kernel(const float* __restrict__ s,
                                                   unsigned short* __restrict__ d, int n4) {
  int i = blockIdx.x * 256 + threadIdx.x;
  if (i >= n4) return;
  float4 v = reinterpret_cast<const float4*>(s)[i];
  ushort4 o;
  o.x = f2b(v.x); o.y = f2b(v.y); o.z = f2b(v.z); o.w = f2b(v.w);
  reinterpret_cast<ushort4*>(d)[i] = o;
}

__global__ __launch_bounds__(256) void sincos_kernel(float* __restrict__ st,
                                                     float* __restrict__ ct, int total) {
  int i = blockIdx.x * 256 + threadIdx.x;
  if (i >= total) return;
  int n = i >> 5, j = i & 31;
  float inv = powf(10000.0f, -(float)j * (1.0f / 32.0f));
  float ang = (float)n * inv;
  st[i] = sinf(ang);
  ct[i] = cosf(ang);
}

// ---------- GEMM: C[M][N] = A[M][K] * B[N][K]^T (+bias), bf16 in, f32 acc ----------
template <int OUTF32>
__global__ __launch_bounds__(256) void gemm_bt(const unsigned short* __restrict__ A,
                                               const unsigned short* __restrict__ B,
                                               void* __restrict__ C,
                                               const float* __restrict__ bias,
                                               int M, int N, int K) {
  __shared__ __align__(16) unsigned short As[128 * 32];
  __shared__ __align__(16) unsigned short Bs[128 * 32];
  const int tid = threadIdx.x;
  const int lane = tid & 63, wave = tid >> 6;
  const int wr = wave >> 1, wc = wave & 1;
  const int bm = blockIdx.y * 128, bn = blockIdx.x * 128;
  const int lr = lane & 15, lk = lane >> 4;
  f32x4 acc[4][4] = {};

  for (int k0 = 0; k0 < K; k0 += 32) {
#pragma unroll
    for (int i = 0; i < 2; ++i) {
      int idx = i * 256 + tid;
      int row = idx >> 2, c8 = (idx & 3) * 8;
      gload_lds16(A + (size_t)(bm + row) * K + k0 + c8, &As[(i * 256 + wave * 64) * 8]);
      gload_lds16(B + (size_t)(bn + row) * K + k0 + c8, &Bs[(i * 256 + wave * 64) * 8]);
    }
    __syncthreads();
    bf16x8 af[4], bfr[4];
#pragma unroll
    for (int mi = 0; mi < 4; ++mi)
      af[mi] = ldfrag(&As[(wr * 64 + mi * 16 + lr) * 32 + lk * 8]);
#pragma unroll
    for (int ni = 0; ni < 4; ++ni)
      bfr[ni] = ldfrag(&Bs[(wc * 64 + ni * 16 + lr) * 32 + lk * 8]);
#pragma unroll
    for (int mi = 0; mi < 4; ++mi)
#pragma unroll
      for (int ni = 0; ni < 4; ++ni)
        acc[mi][ni] = __builtin_amdgcn_mfma_f32_16x16x32_bf16(af[mi], bfr[ni], acc[mi][ni], 0, 0, 0);
    __syncthreads();
  }

#pragma unroll
  for (int mi = 0; mi < 4; ++mi) {
#pragma unroll
    for (int ni = 0; ni < 4; ++ni) {
      int col = bn + wc * 64 + ni * 16 + lr;
      float bv = bias ? bias[col] : 0.0f;
#pragma unroll
      for (int r = 0; r < 4; ++r) {
        int row = bm + wr * 64 + mi * 16 + lk * 4 + r;
        float v = acc[mi][ni][r] + bv;
        if (OUTF32)
          reinterpret_cast<float*>(C)[(size_t)row * N + col] = v;
        else
          reinterpret_cast<unsigned short*>(C)[(size_t)row * N + col] = f2b(v);
      }
    }
  }
}

// ---------- RoPE: qkv[B*N][3072] -> Qo/Ko [B*16][N][64] ----------
// q pre-scaled by log2(e)/sqrt(D) so flash softmax runs in exp2 space.
__global__ __launch_bounds__(256) void rope_kernel(const unsigned short* __restrict__ qkv,
                                                   const float* __restrict__ st,
                                                   const float* __restrict__ ct,
                                                   unsigned short* __restrict__ Qo,
                                                   unsigned short* __restrict__ Ko, int N) {
  const int lane = threadIdx.x & 63;
  const int gw = (int)((blockIdx.x * 256 + threadIdx.x) >> 6);
  const int total = 2 * 2 * N * 16;
  if (gw >= total) return;
  const int which = gw / (2 * N * 16);  // 0=q, 1=k
  int rem = gw - which * (2 * N * 16);
  const int b = rem / (N * 16);
  rem -= b * (N * 16);
  const int n = rem >> 4, h = rem & 15;
  const int d = lane;
  float v = b2f(qkv[((size_t)(b * N + n)) * 3072 + which * 1024 + h * 64 + d]);
  const int j = d & 31;
  float c = ct[n * 32 + j], s = st[n * 32 + j];
  int partner = (d < 32) ? (2 * d + 1) : (2 * (d - 32));
  float pv = __shfl(v, partner, 64);
  float res = (d < 32) ? (v * c - pv * s) : (v * c + pv * s);
  if (which == 0) res *= 0.18033688f;  // (1/8) * log2(e)
  unsigned short* dst = which ? Ko : Qo;
  dst[(((size_t)(b * 16 + h)) * N + n) * 64 + d] = f2b(res);
}

// ---------- V transpose: qkv v-part [n][d] -> Vt[bh][d][n] ----------
__global__ __launch_bounds__(256) void vtrans_kernel(const unsigned short* __restrict__ qkv,
                                                     unsigned short* __restrict__ Vt, int N) {
  __shared__ __align__(16) unsigned short T[64][80];
  const int bh = blockIdx.y, b = bh >> 4, h = bh & 15;
  const int n0 = blockIdx.x * 64;
  const int tid = threadIdx.x;
#pragma unroll
  for (int i = 0; i < 2; ++i) {
    int idx = i * 256 + tid;
    int row = idx >> 3, c8 = (idx & 7) * 8;
    int4 v = *reinterpret_cast<const int4*>(
        &qkv[((size_t)(b * N + n0 + row)) * 3072 + 2048 + h * 64 + c8]);
    *reinterpret_cast<int4*>(&T[row][c8]) = v;
  }
  __syncthreads();
#pragma unroll
  for (int i = 0; i < 2; ++i) {
    int idx = i * 256 + tid;
    int d = idx >> 3, n8 = (idx & 7) * 8;
    int4 ov;
    ov.x = (int)T[n8 + 0][d] | ((int)T[n8 + 1][d] << 16);
    ov.y = (int)T[n8 + 2][d] | ((int)T[n8 + 3][d] << 16);
    ov.z = (int)T[n8 + 4][d] | ((int)T[n8 + 5][d] << 16);
    ov.w = (int)T[n8 + 6][d] | ((int)T[n8 + 7][d] << 16);
    *reinterpret_cast<int4*>(&Vt[((size_t)bh * 64 + d) * N + n0 + n8]) = ov;
  }
}

// ---------- Flash attention ----------
// Q/K [bh][N][64] (q pre-scaled, exp2 space), Vt [bh][64][N] -> Out bf16 [B][N][1024]
// Block: 4 waves x 32 q-rows = 128-row q-tile. K/V double-buffered in LDS with
// XOR-swizzled layout (byte ^= (row&7)<<4 within 128B rows) to kill the 16-way
// ds_read_b128 bank conflicts; same swizzle on the per-wave P tile.
__global__ __launch_bounds__(256) void flash_kernel(const unsigned short* __restrict__ Q,
                                                    const unsigned short* __restrict__ Kb,
                                                    const unsigned short* __restrict__ Vt,
                                                    unsigned short* __restrict__ Out, int N) {
  __shared__ __align__(16) unsigned short Ks[2][64 * 64];
  __shared__ __align__(16) unsigned short Vs[2][64 * 64];  // [d][k] swizzled
  __shared__ __align__(16) unsigned short Ps[4][32 * 64];  // per-wave P, swizzled
  const int tid = threadIdx.x;
  const int lane = tid & 63, wave = tid >> 6;
  const int lr = lane & 15, lk = lane >> 4;
  const int bh = blockIdx.y;
  const int qt = gridDim.x - 1 - blockIdx.x;  // biggest tiles dispatch first
  const int qb0 = qt * 128;
  const unsigned short* Qh = Q + (size_t)bh * N * 64;
  const unsigned short* Kh = Kb + (size_t)bh * N * 64;
  const unsigned short* Vh = Vt + (size_t)bh * 64 * N;

  const int wrow0 = qb0 + wave * 32;
  const int wmax = wrow0 + 31;

  bf16x8 qf[2][2];
#pragma unroll
  for (int mi = 0; mi < 2; ++mi)
#pragma unroll
    for (int c = 0; c < 2; ++c)
      qf[mi][c] = ldfrag(&Qh[(size_t)(wrow0 + mi * 16 + lr) * 64 + c * 32 + lk * 8]);

  f32x4 oacc[2][4] = {};
  float m_run[2][4], l_run[2][4];
#pragma unroll
  for (int mi = 0; mi < 2; ++mi)
#pragma unroll
    for (int r = 0; r < 4; ++r) { m_run[mi][r] = -INFINITY; l_run[mi][r] = 0.0f; }

  // stage one 64x64 K tile + 64x64 V tile into buf, pre-swizzled source
  auto stage = [&](int buf, int t) {
    const int k0 = t * 64;
#pragma unroll
    for (int i = 0; i < 2; ++i) {
      int idx = i * 256 + tid;
      int row = idx >> 3;
      int colb = (idx & 7) * 16;
      int scol = (colb ^ ((row & 7) << 4)) >> 1;  // source col in elems
      gload_lds16(Kh + (size_t)(k0 + row) * 64 + scol, &Ks[buf][(size_t)(i * 256 + wave * 64) * 8]);
      gload_lds16(Vh + (size_t)row * N + k0 + scol, &Vs[buf][(size_t)(i * 256 + wave * 64) * 8]);
    }
  };

  const int nt = 2 * qt + 2;
  stage(0, 0);
  __syncthreads();

  int buf = 0;
  for (int t = 0; t < nt; ++t) {
    if (t + 1 < nt) stage(buf ^ 1, t + 1);  // loads fly during compute
    const int k0 = t * 64;
    if (k0 <= wmax) {
      // S = q @ k^T
      f32x4 s[2][4] = {};
#pragma unroll
      for (int ni = 0; ni < 4; ++ni) {
        const int R = ni * 16 + lr;
        const int sw = (R & 7) << 4;
#pragma unroll
        for (int c = 0; c < 2; ++c) {
          bf16x8 kf = ldfrag(&Ks[buf][R * 64 + (((c * 64 + lk * 16) ^ sw) >> 1)]);
#pragma unroll
          for (int mi = 0; mi < 2; ++mi)
            s[mi][ni] = __builtin_amdgcn_mfma_f32_16x16x32_bf16(qf[mi][c], kf, s[mi][ni], 0, 0, 0);
        }
      }

      if (k0 + 63 > wrow0) {  // (possibly) diagonal: causal mask
#pragma unroll
        for (int mi = 0; mi < 2; ++mi)
#pragma unroll
          for (int ni = 0; ni < 4; ++ni)
#pragma unroll
            for (int r = 0; r < 4; ++r)
              if (k0 + ni * 16 + lr > wrow0 + mi * 16 + lk * 4 + r) s[mi][ni][r] = -INFINITY;
      }

      // online softmax (exp2 space; scale folded into q)
      unsigned short* Pw = &Ps[wave][0];
#pragma unroll
      for (int mi = 0; mi < 2; ++mi) {
        float alpha[4];
#pragma unroll
        for (int r = 0; r < 4; ++r) {
          float mx = fmaxf(fmaxf(s[mi][0][r], s[mi][1][r]), fmaxf(s[mi][2][r], s[mi][3][r]));
#pragma unroll
          for (int off = 1; off < 16; off <<= 1) mx = fmaxf(mx, __shfl_xor(mx, off, 64));
          float nm = fmaxf(m_run[mi][r], mx);
          alpha[r] = __builtin_amdgcn_exp2f(m_run[mi][r] - nm);
          m_run[mi][r] = nm;
        }
        float rs[4] = {0.f, 0.f, 0.f, 0.f};
#pragma unroll
        for (int ni = 0; ni < 4; ++ni)
#pragma unroll
          for (int r = 0; r < 4; ++r) {
            float p = __builtin_amdgcn_exp2f(s[mi][ni][r] - m_run[mi][r]);
            s[mi][ni][r] = p;
            rs[r] += p;
          }
#pragma unroll
        for (int r = 0; r < 4; ++r) {
          float t2 = rs[r];
#pragma unroll
          for (int off = 1; off < 16; off <<= 1) t2 += __shfl_xor(t2, off, 64);
          l_run[mi][r] = l_run[mi][r] * alpha[r] + t2;
#pragma unroll
          for (int ni = 0; ni < 4; ++ni) oacc[mi][ni][r] *= alpha[r];
        }
        // P -> LDS (bf16, swizzled rows)
#pragma unroll
        for (int ni = 0; ni < 4; ++ni)
#pragma unroll
          for (int r = 0; r < 4; ++r) {
            int row = mi * 16 + lk * 4 + r;
            int colb = (ni * 16 + lr) * 2;
            Pw[row * 64 + ((colb ^ ((row & 7) << 4)) >> 1)] = f2b(s[mi][ni][r]);
          }
      }

      // O += P @ V
#pragma unroll
      for (int c = 0; c < 2; ++c) {
        const int cb = c * 64 + lk * 16;
        bf16x8 vf[4];
#pragma unroll
        for (int ni = 0; ni < 4; ++ni) {
          const int RV = ni * 16 + lr;
          vf[ni] = ldfrag(&Vs[buf][RV * 64 + ((cb ^ ((RV & 7) << 4)) >> 1)]);
        }
#pragma unroll
        for (int mi = 0; mi < 2; ++mi) {
          const int R = mi * 16 + lr;
          bf16x8 pf = ldfrag(&Pw[R * 64 + ((cb ^ ((R & 7) << 4)) >> 1)]);
#pragma unroll
          for (int ni = 0; ni < 4; ++ni)
            oacc[mi][ni] = __builtin_amdgcn_mfma_f32_16x16x32_bf16(pf, vf[ni], oacc[mi][ni], 0, 0, 0);
        }
      }
    }
    __syncthreads();
    buf ^= 1;
  }

  const int b = bh >> 4, h = bh & 15;
#pragma unroll
  for (int mi = 0; mi < 2; ++mi)
#pragma unroll
    for (int ni = 0; ni < 4; ++ni)
#pragma unroll
      for (int r = 0; r < 4; ++r) {
        float v = oacc[mi][ni][r] / l_run[mi][r];
        int n = wrow0 + mi * 16 + lk * 4 + r;
        Out[((size_t)(b * N + n)) * 1024 + h * 64 + ni * 16 + lr] = f2b(v);
      }
}

// ---------- launch ----------
extern "C" void kernel_launch(void* const* d_in, const int* in_sizes, int n_in,
                              void* d_out, int out_size, void* d_ws, size_t ws_size,
                              hipStream_t stream) {
  const int B = 2, N = 2048, E = 1024, C = 1024, NC = 3072;
  const int M = B * N;  // 4096

  const float* x  = (const float*)d_in[0];
  const float* Wq = (const float*)d_in[1];
  const float* bq = (const float*)d_in[2];
  const float* Wk = (const float*)d_in[3];
  const float* bk = (const float*)d_in[4];
  const float* Wv = (const float*)d_in[5];
  const float* bv = (const float*)d_in[6];
  const float* Wo = (const float*)d_in[7];
  const float* bo = (const float*)d_in[8];

  char* w = (char*)d_ws;
  size_t off = 0;
  auto alloc = [&](size_t bytes) {
    void* p = w + off;
    off += (bytes + 255) & ~(size_t)255;
    return p;
  };
  unsigned short* xb    = (unsigned short*)alloc((size_t)M * E * 2);
  unsigned short* wqkv  = (unsigned short*)alloc((size_t)NC * E * 2);
  unsigned short* wob   = (unsigned short*)alloc((size_t)E * C * 2);
  unsigned short* qkvb  = (unsigned short*)alloc((size_t)M * NC * 2);
  unsigned short* qb    = (unsigned short*)alloc((size_t)B * 16 * N * 64 * 2);
  unsigned short* kb    = (unsigned short*)alloc((size_t)B * 16 * N * 64 * 2);
  unsigned short* vt    = (unsigned short*)alloc((size_t)B * 16 * 64 * N * 2);
  unsigned short* attnb = (unsigned short*)alloc((size_t)M * C * 2);
  float* sin_t   = (float*)alloc((size_t)N * 32 * 4);
  float* cos_t   = (float*)alloc((size_t)N * 32 * 4);
  float* biasqkv = (float*)alloc((size_t)NC * 4);

  hipMemcpyAsync(biasqkv,         bq, C * sizeof(float), hipMemcpyDeviceToDevice, stream);
  hipMemcpyAsync(biasqkv + C,     bk, C * sizeof(float), hipMemcpyDeviceToDevice, stream);
  hipMemcpyAsync(biasqkv + 2 * C, bv, C * sizeof(float), hipMemcpyDeviceToDevice, stream);

  int n1 = M * E / 4;
  cast_kernel<<<(n1 + 255) / 256, 256, 0, stream>>>(x, xb, n1);
  int n2 = C * E / 4;
  cast_kernel<<<(n2 + 255) / 256, 256, 0, stream>>>(Wq, wqkv, n2);
  cast_kernel<<<(n2 + 255) / 256, 256, 0, stream>>>(Wk, wqkv + (size_t)C * E, n2);
  cast_kernel<<<(n2 + 255) / 256, 256, 0, stream>>>(Wv, wqkv + (size_t)2 * C * E, n2);
  cast_kernel<<<(n2 + 255) / 256, 256, 0, stream>>>(Wo, wob, n2);

  int n3 = N * 32;
  sincos_kernel<<<(n3 + 255) / 256, 256, 0, stream>>>(sin_t, cos_t, n3);

  // QKV projection: [4096][1024] x [3072][1024]^T -> bf16 [4096][3072]
  gemm_bt<0><<<dim3(NC / 128, M / 128), 256, 0, stream>>>(xb, wqkv, qkvb, biasqkv, M, NC, E);

  // RoPE + layout to [bh][N][64]
  int nwaves = 2 * B * N * 16;
  rope_kernel<<<nwaves / 4, 256, 0, stream>>>(qkvb, sin_t, cos_t, qb, kb, N);

  // V transpose to [bh][64][N]
  vtrans_kernel<<<dim3(N / 64, B * 16), 256, 0, stream>>>(qkvb, vt, N);

  // causal flash attention -> bf16 [B*N][1024] (128-row q-tiles)
  flash_kernel<<<dim3(N / 128, B * 16), 256, 0, stream>>>(qb, kb, vt, attnb, N);

  // output projection: [4096][1024] x [1024][1024]^T + bo -> f32 d_out
  gemm_bt<1><<<dim3(E / 128, M / 128), 256, 0, stream>>>(attnb, wob, d_out, bo, M, E, C);
}

// Round 3
// 201.551 us; speedup vs baseline: 1.3140x; 1.1522x over previous
//
#include <hip/hip_runtime.h>
#include <hip/hip_bf16.h>
#include <cstdint>
#include <cstddef>

// ---------- types ----------
using bf16x8 = __attribute__((ext_vector_type(8))) __bf16;
using f32x4  = __attribute__((ext_vector_type(4))) float;

__device__ __forceinline__ float b2f(unsigned short u) {
  union { unsigned u; float f; } x; x.u = ((unsigned)u) << 16; return x.f;
}
__device__ __forceinline__ unsigned short f2b(float f) {
  union { float f; unsigned u; } x; x.f = f;
  unsigned r = x.u + 0x7fffu + ((x.u >> 16) & 1u);
  return (unsigned short)(r >> 16);
}
// truncating cast: safe for P because l is computed (via MFMA) from the SAME bf16 values.
__device__ __forceinline__ unsigned short f2b_trunc(float f) {
  union { float f; unsigned u; } x; x.f = f;
  return (unsigned short)(x.u >> 16);
}

// async global->LDS, 16B per lane. dst must be wave-uniform base (HW adds lane*16).
__device__ __forceinline__ void gload_lds16(const void* g, void* l) {
  __builtin_amdgcn_global_load_lds(
      (const __attribute__((address_space(1))) void*)g,
      (__attribute__((address_space(3))) void*)l, 16, 0, 0);
}

__device__ __forceinline__ bf16x8 ldfrag(const unsigned short* p) {
  return *reinterpret_cast<const bf16x8*>(p);
}

// ---------- prep kernels ----------
__global__ __launch_bounds__(256) void cast_kernel(const float* __restrict__ s,
                                                   unsigned short* __restrict__ d, int n4) {
  int i = blockIdx.x * 256 + threadIdx.x;
  if (i >= n4) return;
  float4 v = reinterpret_cast<const float4*>(s)[i];
  ushort4 o;
  o.x = f2b(v.x); o.y = f2b(v.y); o.z = f2b(v.z); o.w = f2b(v.w);
  reinterpret_cast<ushort4*>(d)[i] = o;
}

__global__ __launch_bounds__(256) void sincos_kernel(float* __restrict__ st,
                                                     float* __restrict__ ct, int total) {
  int i = blockIdx.x * 256 + threadIdx.x;
  if (i >= total) return;
  int n = i >> 5, j = i & 31;
  float inv = powf(10000.0f, -(float)j * (1.0f / 32.0f));
  float ang = (float)n * inv;
  st[i] = sinf(ang);
  ct[i] = cosf(ang);
}

// ---------- GEMM: C[M][N] = A[M][K] * B[N][K]^T (+bias), bf16 in, f32 acc ----------
template <int OUTF32>
__global__ __launch_bounds__(256) void gemm_bt(const unsigned short* __restrict__ A,
                                               const unsigned short* __restrict__ B,
                                               void* __restrict__ C,
                                               const float* __restrict__ bias,
                                               int M, int N, int K) {
  __shared__ __align__(16) unsigned short As[128 * 32];
  __shared__ __align__(16) unsigned short Bs[128 * 32];
  const int tid = threadIdx.x;
  const int lane = tid & 63, wave = tid >> 6;
  const int wr = wave >> 1, wc = wave & 1;
  const int bm = blockIdx.y * 128, bn = blockIdx.x * 128;
  const int lr = lane & 15, lk = lane >> 4;
  f32x4 acc[4][4] = {};

  for (int k0 = 0; k0 < K; k0 += 32) {
#pragma unroll
    for (int i = 0; i < 2; ++i) {
      int idx = i * 256 + tid;
      int row = idx >> 2, c8 = (idx & 3) * 8;
      gload_lds16(A + (size_t)(bm + row) * K + k0 + c8, &As[(i * 256 + wave * 64) * 8]);
      gload_lds16(B + (size_t)(bn + row) * K + k0 + c8, &Bs[(i * 256 + wave * 64) * 8]);
    }
    __syncthreads();
    bf16x8 af[4], bfr[4];
#pragma unroll
    for (int mi = 0; mi < 4; ++mi)
      af[mi] = ldfrag(&As[(wr * 64 + mi * 16 + lr) * 32 + lk * 8]);
#pragma unroll
    for (int ni = 0; ni < 4; ++ni)
      bfr[ni] = ldfrag(&Bs[(wc * 64 + ni * 16 + lr) * 32 + lk * 8]);
#pragma unroll
    for (int mi = 0; mi < 4; ++mi)
#pragma unroll
      for (int ni = 0; ni < 4; ++ni)
        acc[mi][ni] = __builtin_amdgcn_mfma_f32_16x16x32_bf16(af[mi], bfr[ni], acc[mi][ni], 0, 0, 0);
    __syncthreads();
  }

#pragma unroll
  for (int mi = 0; mi < 4; ++mi) {
#pragma unroll
    for (int ni = 0; ni < 4; ++ni) {
      int col = bn + wc * 64 + ni * 16 + lr;
      float bv = bias ? bias[col] : 0.0f;
#pragma unroll
      for (int r = 0; r < 4; ++r) {
        int row = bm + wr * 64 + mi * 16 + lk * 4 + r;
        float v = acc[mi][ni][r] + bv;
        if (OUTF32)
          reinterpret_cast<float*>(C)[(size_t)row * N + col] = v;
        else
          reinterpret_cast<unsigned short*>(C)[(size_t)row * N + col] = f2b(v);
      }
    }
  }
}

// ---------- RoPE: qkv[B*N][3072] -> Qo/Ko [B*16][N][64] ----------
// q pre-scaled by log2(e)/sqrt(D) so flash softmax runs in exp2 space.
__global__ __launch_bounds__(256) void rope_kernel(const unsigned short* __restrict__ qkv,
                                                   const float* __restrict__ st,
                                                   const float* __restrict__ ct,
                                                   unsigned short* __restrict__ Qo,
                                                   unsigned short* __restrict__ Ko, int N) {
  const int lane = threadIdx.x & 63;
  const int gw = (int)((blockIdx.x * 256 + threadIdx.x) >> 6);
  const int total = 2 * 2 * N * 16;
  if (gw >= total) return;
  const int which = gw / (2 * N * 16);  // 0=q, 1=k
  int rem = gw - which * (2 * N * 16);
  const int b = rem / (N * 16);
  rem -= b * (N * 16);
  const int n = rem >> 4, h = rem & 15;
  const int d = lane;
  float v = b2f(qkv[((size_t)(b * N + n)) * 3072 + which * 1024 + h * 64 + d]);
  const int j = d & 31;
  float c = ct[n * 32 + j], s = st[n * 32 + j];
  int partner = (d < 32) ? (2 * d + 1) : (2 * (d - 32));
  float pv = __shfl(v, partner, 64);
  float res = (d < 32) ? (v * c - pv * s) : (v * c + pv * s);
  if (which == 0) res *= 0.18033688f;  // (1/8) * log2(e)
  unsigned short* dst = which ? Ko : Qo;
  dst[(((size_t)(b * 16 + h)) * N + n) * 64 + d] = f2b(res);
}

// ---------- V transpose: qkv v-part [n][d] -> Vt[bh][d][n] ----------
__global__ __launch_bounds__(256) void vtrans_kernel(const unsigned short* __restrict__ qkv,
                                                     unsigned short* __restrict__ Vt, int N) {
  __shared__ __align__(16) unsigned short T[64][80];
  const int bh = blockIdx.y, b = bh >> 4, h = bh & 15;
  const int n0 = blockIdx.x * 64;
  const int tid = threadIdx.x;
#pragma unroll
  for (int i = 0; i < 2; ++i) {
    int idx = i * 256 + tid;
    int row = idx >> 3, c8 = (idx & 7) * 8;
    int4 v = *reinterpret_cast<const int4*>(
        &qkv[((size_t)(b * N + n0 + row)) * 3072 + 2048 + h * 64 + c8]);
    *reinterpret_cast<int4*>(&T[row][c8]) = v;
  }
  __syncthreads();
#pragma unroll
  for (int i = 0; i < 2; ++i) {
    int idx = i * 256 + tid;
    int d = idx >> 3, n8 = (idx & 7) * 8;
    int4 ov;
    ov.x = (int)T[n8 + 0][d] | ((int)T[n8 + 1][d] << 16);
    ov.y = (int)T[n8 + 2][d] | ((int)T[n8 + 3][d] << 16);
    ov.z = (int)T[n8 + 4][d] | ((int)T[n8 + 5][d] << 16);
    ov.w = (int)T[n8 + 6][d] | ((int)T[n8 + 7][d] << 16);
    *reinterpret_cast<int4*>(&Vt[((size_t)bh * 64 + d) * N + n0 + n8]) = ov;
  }
}

// ---------- Flash attention ----------
// Q/K [bh][N][64] (q pre-scaled, exp2 space), Vt [bh][64][N] -> Out bf16 [B][N][1024]
// 4 waves x 32 q-rows = 128-row q-tile. K/V double-buffered, XOR-swizzled LDS.
// l computed via MFMA with an all-ones B operand (no sum shuffles); defer-max
// rescale (THR=8 in log2 units); complementary qt pairing for CU load balance.
__global__ __launch_bounds__(256) void flash_kernel(const unsigned short* __restrict__ Q,
                                                    const unsigned short* __restrict__ Kb,
                                                    const unsigned short* __restrict__ Vt,
                                                    unsigned short* __restrict__ Out, int N) {
  __shared__ __align__(16) unsigned short Ks[2][64 * 64];
  __shared__ __align__(16) unsigned short Vs[2][64 * 64];  // [d][k] swizzled
  __shared__ __align__(16) unsigned short Ps[4][32 * 64];  // per-wave P, swizzled
  const int tid = threadIdx.x;
  const int lane = tid & 63, wave = tid >> 6;
  const int lr = lane & 15, lk = lane >> 4;
  const int bh = blockIdx.y;
  // complementary pairing: co-resident blocks (c, c+256) differ in bit4 of y ->
  // one takes qt=x, the other 15-x => uniform per-CU work.
  const int qt = ((blockIdx.y >> 4) & 1) ? (int)blockIdx.x
                                         : (int)(gridDim.x - 1 - blockIdx.x);
  const int qb0 = qt * 128;
  const unsigned short* Qh = Q + (size_t)bh * N * 64;
  const unsigned short* Kh = Kb + (size_t)bh * N * 64;
  const unsigned short* Vh = Vt + (size_t)bh * 64 * N;

  const int wrow0 = qb0 + wave * 32;
  const int wmax = wrow0 + 31;

  // stage one 64x64 K tile + 64x64 V tile into buf, pre-swizzled source
  auto stage = [&](int buf, int t) {
    const int k0 = t * 64;
#pragma unroll
    for (int i = 0; i < 2; ++i) {
      int idx = i * 256 + tid;
      int row = idx >> 3;
      int colb = (idx & 7) * 16;
      int scol = (colb ^ ((row & 7) << 4)) >> 1;  // source col in elems
      gload_lds16(Kh + (size_t)(k0 + row) * 64 + scol, &Ks[buf][(size_t)(i * 256 + wave * 64) * 8]);
      gload_lds16(Vh + (size_t)row * N + k0 + scol, &Vs[buf][(size_t)(i * 256 + wave * 64) * 8]);
    }
  };

  stage(0, 0);

  bf16x8 qf[2][2];
#pragma unroll
  for (int mi = 0; mi < 2; ++mi)
#pragma unroll
    for (int c = 0; c < 2; ++c)
      qf[mi][c] = ldfrag(&Qh[(size_t)(wrow0 + mi * 16 + lr) * 64 + c * 32 + lk * 8]);

  // all-ones bf16 fragment for the l-sum MFMA
  bf16x8 ones;
  {
    union { unsigned short u; __bf16 b; } one; one.u = 0x3F80;
#pragma unroll
    for (int j = 0; j < 8; ++j) ones[j] = one.b;
  }

  f32x4 oacc[2][4] = {};
  f32x4 lacc[2] = {};
  float m_run[2][4];
#pragma unroll
  for (int mi = 0; mi < 2; ++mi)
#pragma unroll
    for (int r = 0; r < 4; ++r) m_run[mi][r] = -INFINITY;

  const int nt = 2 * qt + 2;
  __syncthreads();

  int buf = 0;
  for (int t = 0; t < nt; ++t) {
    if (t + 1 < nt) stage(buf ^ 1, t + 1);  // loads fly during compute
    const int k0 = t * 64;
    if (k0 <= wmax) {
      // S = q @ k^T
      f32x4 s[2][4] = {};
      __builtin_amdgcn_s_setprio(1);
#pragma unroll
      for (int ni = 0; ni < 4; ++ni) {
        const int R = ni * 16 + lr;
        const int sw = (R & 7) << 4;
#pragma unroll
        for (int c = 0; c < 2; ++c) {
          bf16x8 kf = ldfrag(&Ks[buf][R * 64 + (((c * 64 + lk * 16) ^ sw) >> 1)]);
#pragma unroll
          for (int mi = 0; mi < 2; ++mi)
            s[mi][ni] = __builtin_amdgcn_mfma_f32_16x16x32_bf16(qf[mi][c], kf, s[mi][ni], 0, 0, 0);
        }
      }
      __builtin_amdgcn_s_setprio(0);

      if (k0 + 63 > wrow0) {  // (possibly) diagonal: causal mask
#pragma unroll
        for (int mi = 0; mi < 2; ++mi)
#pragma unroll
          for (int ni = 0; ni < 4; ++ni)
#pragma unroll
            for (int r = 0; r < 4; ++r)
              if (k0 + ni * 16 + lr > wrow0 + mi * 16 + lk * 4 + r) s[mi][ni][r] = -INFINITY;
      }

      // online softmax, exp2 space, defer-max (THR=8)
      unsigned short* Pw = &Ps[wave][0];
#pragma unroll
      for (int mi = 0; mi < 2; ++mi) {
        float pmax[4];
        bool okl = true;
#pragma unroll
        for (int r = 0; r < 4; ++r) {
          float mx = fmaxf(fmaxf(s[mi][0][r], s[mi][1][r]), fmaxf(s[mi][2][r], s[mi][3][r]));
#pragma unroll
          for (int off = 1; off < 16; off <<= 1) mx = fmaxf(mx, __shfl_xor(mx, off, 64));
          pmax[r] = mx;
          okl = okl && (mx - m_run[mi][r] <= 8.0f);
        }
        if (!__all(okl)) {  // rescale path (rare after first tile)
#pragma unroll
          for (int r = 0; r < 4; ++r) {
            float nm = fmaxf(m_run[mi][r], pmax[r]);
            float alpha = __builtin_amdgcn_exp2f(m_run[mi][r] - nm);
            m_run[mi][r] = nm;
#pragma unroll
            for (int ni = 0; ni < 4; ++ni) oacc[mi][ni][r] *= alpha;
            lacc[mi][r] *= alpha;
          }
        }
        // P = exp2(s - m), truncate to bf16, write swizzled LDS
#pragma unroll
        for (int ni = 0; ni < 4; ++ni)
#pragma unroll
          for (int r = 0; r < 4; ++r) {
            float p = __builtin_amdgcn_exp2f(s[mi][ni][r] - m_run[mi][r]);
            int row = mi * 16 + lk * 4 + r;
            int colb = (ni * 16 + lr) * 2;
            Pw[row * 64 + ((colb ^ ((row & 7) << 4)) >> 1)] = f2b_trunc(p);
          }
      }

      // O += P @ V ; l += P @ ones (row-sum via MFMA, no shuffles)
      __builtin_amdgcn_s_setprio(1);
#pragma unroll
      for (int c = 0; c < 2; ++c) {
        const int cb = c * 64 + lk * 16;
        bf16x8 vf[4];
#pragma unroll
        for (int ni = 0; ni < 4; ++ni) {
          const int RV = ni * 16 + lr;
          vf[ni] = ldfrag(&Vs[buf][RV * 64 + ((cb ^ ((RV & 7) << 4)) >> 1)]);
        }
#pragma unroll
        for (int mi = 0; mi < 2; ++mi) {
          const int R = mi * 16 + lr;
          bf16x8 pf = ldfrag(&Pw[R * 64 + ((cb ^ ((R & 7) << 4)) >> 1)]);
          lacc[mi] = __builtin_amdgcn_mfma_f32_16x16x32_bf16(pf, ones, lacc[mi], 0, 0, 0);
#pragma unroll
          for (int ni = 0; ni < 4; ++ni)
            oacc[mi][ni] = __builtin_amdgcn_mfma_f32_16x16x32_bf16(pf, vf[ni], oacc[mi][ni], 0, 0, 0);
        }
      }
      __builtin_amdgcn_s_setprio(0);
    }
    __syncthreads();
    buf ^= 1;
  }

  const int b = bh >> 4, h = bh & 15;
#pragma unroll
  for (int mi = 0; mi < 2; ++mi) {
    float rl[4];
#pragma unroll
    for (int r = 0; r < 4; ++r) rl[r] = 1.0f / lacc[mi][r];
#pragma unroll
    for (int ni = 0; ni < 4; ++ni)
#pragma unroll
      for (int r = 0; r < 4; ++r) {
        float v = oacc[mi][ni][r] * rl[r];
        int n = wrow0 + mi * 16 + lk * 4 + r;
        Out[((size_t)(b * N + n)) * 1024 + h * 64 + ni * 16 + lr] = f2b(v);
      }
  }
}

// ---------- launch ----------
extern "C" void kernel_launch(void* const* d_in, const int* in_sizes, int n_in,
                              void* d_out, int out_size, void* d_ws, size_t ws_size,
                              hipStream_t stream) {
  const int B = 2, N = 2048, E = 1024, C = 1024, NC = 3072;
  const int M = B * N;  // 4096

  const float* x  = (const float*)d_in[0];
  const float* Wq = (const float*)d_in[1];
  const float* bq = (const float*)d_in[2];
  const float* Wk = (const float*)d_in[3];
  const float* bk = (const float*)d_in[4];
  const float* Wv = (const float*)d_in[5];
  const float* bv = (const float*)d_in[6];
  const float* Wo = (const float*)d_in[7];
  const float* bo = (const float*)d_in[8];

  char* w = (char*)d_ws;
  size_t off = 0;
  auto alloc = [&](size_t bytes) {
    void* p = w + off;
    off += (bytes + 255) & ~(size_t)255;
    return p;
  };
  unsigned short* xb    = (unsigned short*)alloc((size_t)M * E * 2);
  unsigned short* wqkv  = (unsigned short*)alloc((size_t)NC * E * 2);
  unsigned short* wob   = (unsigned short*)alloc((size_t)E * C * 2);
  unsigned short* qkvb  = (unsigned short*)alloc((size_t)M * NC * 2);
  unsigned short* qb    = (unsigned short*)alloc((size_t)B * 16 * N * 64 * 2);
  unsigned short* kb    = (unsigned short*)alloc((size_t)B * 16 * N * 64 * 2);
  unsigned short* vt    = (unsigned short*)alloc((size_t)B * 16 * 64 * N * 2);
  unsigned short* attnb = (unsigned short*)alloc((size_t)M * C * 2);
  float* sin_t   = (float*)alloc((size_t)N * 32 * 4);
  float* cos_t   = (float*)alloc((size_t)N * 32 * 4);
  float* biasqkv = (float*)alloc((size_t)NC * 4);

  hipMemcpyAsync(biasqkv,         bq, C * sizeof(float), hipMemcpyDeviceToDevice, stream);
  hipMemcpyAsync(biasqkv + C,     bk, C * sizeof(float), hipMemcpyDeviceToDevice, stream);
  hipMemcpyAsync(biasqkv + 2 * C, bv, C * sizeof(float), hipMemcpyDeviceToDevice, stream);

  int n1 = M * E / 4;
  cast_kernel<<<(n1 + 255) / 256, 256, 0, stream>>>(x, xb, n1);
  int n2 = C * E / 4;
  cast_kernel<<<(n2 + 255) / 256, 256, 0, stream>>>(Wq, wqkv, n2);
  cast_kernel<<<(n2 + 255) / 256, 256, 0, stream>>>(Wk, wqkv + (size_t)C * E, n2);
  cast_kernel<<<(n2 + 255) / 256, 256, 0, stream>>>(Wv, wqkv + (size_t)2 * C * E, n2);
  cast_kernel<<<(n2 + 255) / 256, 256, 0, stream>>>(Wo, wob, n2);

  int n3 = N * 32;
  sincos_kernel<<<(n3 + 255) / 256, 256, 0, stream>>>(sin_t, cos_t, n3);

  // QKV projection: [4096][1024] x [3072][1024]^T -> bf16 [4096][3072]
  gemm_bt<0><<<dim3(NC / 128, M / 128), 256, 0, stream>>>(xb, wqkv, qkvb, biasqkv, M, NC, E);

  // RoPE + layout to [bh][N][64]
  int nwaves = 2 * B * N * 16;
  rope_kernel<<<nwaves / 4, 256, 0, stream>>>(qkvb, sin_t, cos_t, qb, kb, N);

  // V transpose to [bh][64][N]
  vtrans_kernel<<<dim3(N / 64, B * 16), 256, 0, stream>>>(qkvb, vt, N);

  // causal flash attention -> bf16 [B*N][1024] (128-row q-tiles)
  flash_kernel<<<dim3(N / 128, B * 16), 256, 0, stream>>>(qb, kb, vt, attnb, N);

  // output projection: [4096][1024] x [1024][1024]^T + bo -> f32 d_out
  gemm_bt<1><<<dim3(E / 128, M / 128), 256, 0, stream>>>(attnb, wob, d_out, bo, M, E, C);
}

// Round 4
// 198.376 us; speedup vs baseline: 1.3351x; 1.0160x over previous
//
#include <hip/hip_runtime.h>
#include <hip/hip_bf16.h>
#include <cstdint>
#include <cstddef>

// ---------- types ----------
using bf16x8 = __attribute__((ext_vector_type(8))) __bf16;
using f32x4  = __attribute__((ext_vector_type(4))) float;

__device__ __forceinline__ float b2f(unsigned short u) {
  union { unsigned u; float f; } x; x.u = ((unsigned)u) << 16; return x.f;
}
__device__ __forceinline__ unsigned short f2b(float f) {
  union { float f; unsigned u; } x; x.f = f;
  unsigned r = x.u + 0x7fffu + ((x.u >> 16) & 1u);
  return (unsigned short)(r >> 16);
}
// truncating cast: safe for P because l is computed (via MFMA) from the SAME bf16 values.
__device__ __forceinline__ unsigned short f2b_trunc(float f) {
  union { float f; unsigned u; } x; x.f = f;
  return (unsigned short)(x.u >> 16);
}

// async global->LDS, 16B per lane. dst must be wave-uniform base (HW adds lane*16).
__device__ __forceinline__ void gload_lds16(const void* g, void* l) {
  __builtin_amdgcn_global_load_lds(
      (const __attribute__((address_space(1))) void*)g,
      (__attribute__((address_space(3))) void*)l, 16, 0, 0);
}

__device__ __forceinline__ bf16x8 ldfrag(const unsigned short* p) {
  return *reinterpret_cast<const bf16x8*>(p);
}

// ---------- prep kernels ----------
__global__ __launch_bounds__(256) void cast_kernel(const float* __restrict__ s,
                                                   unsigned short* __restrict__ d, int n4) {
  int i = blockIdx.x * 256 + threadIdx.x;
  if (i >= n4) return;
  float4 v = reinterpret_cast<const float4*>(s)[i];
  ushort4 o;
  o.x = f2b(v.x); o.y = f2b(v.y); o.z = f2b(v.z); o.w = f2b(v.w);
  reinterpret_cast<ushort4*>(d)[i] = o;
}

__global__ __launch_bounds__(256) void sincos_kernel(float* __restrict__ st,
                                                     float* __restrict__ ct, int total) {
  int i = blockIdx.x * 256 + threadIdx.x;
  if (i >= total) return;
  int n = i >> 5, j = i & 31;
  float inv = powf(10000.0f, -(float)j * (1.0f / 32.0f));
  float ang = (float)n * inv;
  st[i] = sinf(ang);
  ct[i] = cosf(ang);
}

// ---------- GEMM: C[M][N] = A[M][K] * B[N][K]^T (+bias), bf16 in, f32 acc ----------
template <int OUTF32>
__global__ __launch_bounds__(256) void gemm_bt(const unsigned short* __restrict__ A,
                                               const unsigned short* __restrict__ B,
                                               void* __restrict__ C,
                                               const float* __restrict__ bias,
                                               int M, int N, int K) {
  __shared__ __align__(16) unsigned short As[128 * 32];
  __shared__ __align__(16) unsigned short Bs[128 * 32];
  const int tid = threadIdx.x;
  const int lane = tid & 63, wave = tid >> 6;
  const int wr = wave >> 1, wc = wave & 1;
  const int bm = blockIdx.y * 128, bn = blockIdx.x * 128;
  const int lr = lane & 15, lk = lane >> 4;
  f32x4 acc[4][4] = {};

  for (int k0 = 0; k0 < K; k0 += 32) {
#pragma unroll
    for (int i = 0; i < 2; ++i) {
      int idx = i * 256 + tid;
      int row = idx >> 2, c8 = (idx & 3) * 8;
      gload_lds16(A + (size_t)(bm + row) * K + k0 + c8, &As[(i * 256 + wave * 64) * 8]);
      gload_lds16(B + (size_t)(bn + row) * K + k0 + c8, &Bs[(i * 256 + wave * 64) * 8]);
    }
    __syncthreads();
    bf16x8 af[4], bfr[4];
#pragma unroll
    for (int mi = 0; mi < 4; ++mi)
      af[mi] = ldfrag(&As[(wr * 64 + mi * 16 + lr) * 32 + lk * 8]);
#pragma unroll
    for (int ni = 0; ni < 4; ++ni)
      bfr[ni] = ldfrag(&Bs[(wc * 64 + ni * 16 + lr) * 32 + lk * 8]);
#pragma unroll
    for (int mi = 0; mi < 4; ++mi)
#pragma unroll
      for (int ni = 0; ni < 4; ++ni)
        acc[mi][ni] = __builtin_amdgcn_mfma_f32_16x16x32_bf16(af[mi], bfr[ni], acc[mi][ni], 0, 0, 0);
    __syncthreads();
  }

#pragma unroll
  for (int mi = 0; mi < 4; ++mi) {
#pragma unroll
    for (int ni = 0; ni < 4; ++ni) {
      int col = bn + wc * 64 + ni * 16 + lr;
      float bv = bias ? bias[col] : 0.0f;
#pragma unroll
      for (int r = 0; r < 4; ++r) {
        int row = bm + wr * 64 + mi * 16 + lk * 4 + r;
        float v = acc[mi][ni][r] + bv;
        if (OUTF32)
          reinterpret_cast<float*>(C)[(size_t)row * N + col] = v;
        else
          reinterpret_cast<unsigned short*>(C)[(size_t)row * N + col] = f2b(v);
      }
    }
  }
}

// ---------- RoPE: qkv[B*N][3072] -> Qo/Ko [B*16][N][64] ----------
// q pre-scaled by log2(e)/sqrt(D) so flash softmax runs in exp2 space.
__global__ __launch_bounds__(256) void rope_kernel(const unsigned short* __restrict__ qkv,
                                                   const float* __restrict__ st,
                                                   const float* __restrict__ ct,
                                                   unsigned short* __restrict__ Qo,
                                                   unsigned short* __restrict__ Ko, int N) {
  const int lane = threadIdx.x & 63;
  const int gw = (int)((blockIdx.x * 256 + threadIdx.x) >> 6);
  const int total = 2 * 2 * N * 16;
  if (gw >= total) return;
  const int which = gw / (2 * N * 16);  // 0=q, 1=k
  int rem = gw - which * (2 * N * 16);
  const int b = rem / (N * 16);
  rem -= b * (N * 16);
  const int n = rem >> 4, h = rem & 15;
  const int d = lane;
  float v = b2f(qkv[((size_t)(b * N + n)) * 3072 + which * 1024 + h * 64 + d]);
  const int j = d & 31;
  float c = ct[n * 32 + j], s = st[n * 32 + j];
  int partner = (d < 32) ? (2 * d + 1) : (2 * (d - 32));
  float pv = __shfl(v, partner, 64);
  float res = (d < 32) ? (v * c - pv * s) : (v * c + pv * s);
  if (which == 0) res *= 0.18033688f;  // (1/8) * log2(e)
  unsigned short* dst = which ? Ko : Qo;
  dst[(((size_t)(b * 16 + h)) * N + n) * 64 + d] = f2b(res);
}

// ---------- V transpose: qkv v-part [n][d] -> Vt[bh][d][n] ----------
__global__ __launch_bounds__(256) void vtrans_kernel(const unsigned short* __restrict__ qkv,
                                                     unsigned short* __restrict__ Vt, int N) {
  __shared__ __align__(16) unsigned short T[64][80];
  const int bh = blockIdx.y, b = bh >> 4, h = bh & 15;
  const int n0 = blockIdx.x * 64;
  const int tid = threadIdx.x;
#pragma unroll
  for (int i = 0; i < 2; ++i) {
    int idx = i * 256 + tid;
    int row = idx >> 3, c8 = (idx & 7) * 8;
    int4 v = *reinterpret_cast<const int4*>(
        &qkv[((size_t)(b * N + n0 + row)) * 3072 + 2048 + h * 64 + c8]);
    *reinterpret_cast<int4*>(&T[row][c8]) = v;
  }
  __syncthreads();
#pragma unroll
  for (int i = 0; i < 2; ++i) {
    int idx = i * 256 + tid;
    int d = idx >> 3, n8 = (idx & 7) * 8;
    int4 ov;
    ov.x = (int)T[n8 + 0][d] | ((int)T[n8 + 1][d] << 16);
    ov.y = (int)T[n8 + 2][d] | ((int)T[n8 + 3][d] << 16);
    ov.z = (int)T[n8 + 4][d] | ((int)T[n8 + 5][d] << 16);
    ov.w = (int)T[n8 + 6][d] | ((int)T[n8 + 7][d] << 16);
    *reinterpret_cast<int4*>(&Vt[((size_t)bh * 64 + d) * N + n0 + n8]) = ov;
  }
}

// ---------- Flash attention ----------
// Q/K [bh][N][64] (q pre-scaled, exp2 space), Vt [bh][64][N] -> Out bf16 [B][N][1024]
// 512 threads = 8 waves. Dual q-tile per block: waves 0-3 own qt=x (rows 128x..),
// waves 4-7 own qt=15-x; single shared k-scan (max of the two ranges). Every block
// performs exactly 34 wave-compute-phases -> uniform per-CU work with NO
// co-residency assumption (grid = 256 blocks = 1/CU). K/V double-buffered,
// XOR-swizzled; stage addresses precomputed per-thread (pointer += stride).
__global__ __launch_bounds__(512) void flash_kernel(const unsigned short* __restrict__ Q,
                                                    const unsigned short* __restrict__ Kb,
                                                    const unsigned short* __restrict__ Vt,
                                                    unsigned short* __restrict__ Out, int N) {
  __shared__ __align__(16) unsigned short Ks[2][64 * 64];
  __shared__ __align__(16) unsigned short Vs[2][64 * 64];  // [d][k] swizzled
  __shared__ __align__(16) unsigned short Ps[8][32 * 64];  // per-wave P, swizzled
  const int tid = threadIdx.x;
  const int lane = tid & 63, wave = tid >> 6;
  const int lr = lane & 15, lk = lane >> 4;
  const int bh = blockIdx.y;
  const int x = blockIdx.x;                    // 0..7
  const int grp = wave >> 2, wsub = wave & 3;  // grp0 -> qt=x, grp1 -> qt=15-x
  const int qt = grp ? (15 - x) : x;
  const int qb0 = qt * 128;
  const unsigned short* Qh = Q + (size_t)bh * N * 64;
  const unsigned short* Kh = Kb + (size_t)bh * N * 64;
  const unsigned short* Vh = Vt + (size_t)bh * 64 * N;

  const int wrow0 = qb0 + wsub * 32;
  const int wmax = wrow0 + 31;

  // precomputed per-thread staging pointers (advance by constant per tile)
  const int srow = tid >> 3;
  const int scolb = (tid & 7) * 16;
  const int scol = ((scolb ^ ((srow & 7) << 4)) >> 1);
  const unsigned short* Kg = Kh + (size_t)srow * 64 + scol;
  const unsigned short* Vg = Vh + (size_t)srow * N + scol;

  auto stage = [&](int buf, int t) {
    gload_lds16(Kg + (size_t)t * 4096, &Ks[buf][wave << 9]);
    gload_lds16(Vg + (size_t)t * 64, &Vs[buf][wave << 9]);
  };

  stage(0, 0);

  bf16x8 qf[2][2];
#pragma unroll
  for (int mi = 0; mi < 2; ++mi)
#pragma unroll
    for (int c = 0; c < 2; ++c)
      qf[mi][c] = ldfrag(&Qh[(size_t)(wrow0 + mi * 16 + lr) * 64 + c * 32 + lk * 8]);

  // all-ones bf16 fragment for the l-sum MFMA
  bf16x8 ones;
  {
    union { unsigned short u; __bf16 b; } one; one.u = 0x3F80;
#pragma unroll
    for (int j = 0; j < 8; ++j) ones[j] = one.b;
  }

  f32x4 oacc[2][4] = {};
  f32x4 lacc[2] = {};
  float m_run[2][4];
#pragma unroll
  for (int mi = 0; mi < 2; ++mi)
#pragma unroll
    for (int r = 0; r < 4; ++r) m_run[mi][r] = -INFINITY;

  const int ntMax = 2 * (15 - x) + 2;  // heavy tile's scan length (>= light tile's)
  __syncthreads();

  int buf = 0;
  for (int t = 0; t < ntMax; ++t) {
    if (t + 1 < ntMax) stage(buf ^ 1, t + 1);  // loads fly during compute
    const int k0 = t * 64;
    if (k0 <= wmax) {
      // S = q @ k^T
      f32x4 s[2][4] = {};
      __builtin_amdgcn_s_setprio(1);
#pragma unroll
      for (int ni = 0; ni < 4; ++ni) {
        const int R = ni * 16 + lr;
        const int sw = (R & 7) << 4;
#pragma unroll
        for (int c = 0; c < 2; ++c) {
          bf16x8 kf = ldfrag(&Ks[buf][R * 64 + (((c * 64 + lk * 16) ^ sw) >> 1)]);
#pragma unroll
          for (int mi = 0; mi < 2; ++mi)
            s[mi][ni] = __builtin_amdgcn_mfma_f32_16x16x32_bf16(qf[mi][c], kf, s[mi][ni], 0, 0, 0);
        }
      }
      __builtin_amdgcn_s_setprio(0);

      if (k0 + 63 > wrow0) {  // (possibly) diagonal: causal mask
#pragma unroll
        for (int mi = 0; mi < 2; ++mi)
#pragma unroll
          for (int ni = 0; ni < 4; ++ni)
#pragma unroll
            for (int r = 0; r < 4; ++r)
              if (k0 + ni * 16 + lr > wrow0 + mi * 16 + lk * 4 + r) s[mi][ni][r] = -INFINITY;
      }

      // online softmax, exp2 space, defer-max (THR=8)
      unsigned short* Pw = &Ps[wave][0];
#pragma unroll
      for (int mi = 0; mi < 2; ++mi) {
        float pmax[4];
        bool okl = true;
#pragma unroll
        for (int r = 0; r < 4; ++r) {
          float mx = fmaxf(fmaxf(s[mi][0][r], s[mi][1][r]), fmaxf(s[mi][2][r], s[mi][3][r]));
#pragma unroll
          for (int off = 1; off < 16; off <<= 1) mx = fmaxf(mx, __shfl_xor(mx, off, 64));
          pmax[r] = mx;
          okl = okl && (mx - m_run[mi][r] <= 8.0f);
        }
        if (!__all(okl)) {  // rescale path (rare after first tile)
#pragma unroll
          for (int r = 0; r < 4; ++r) {
            float nm = fmaxf(m_run[mi][r], pmax[r]);
            float alpha = __builtin_amdgcn_exp2f(m_run[mi][r] - nm);
            m_run[mi][r] = nm;
#pragma unroll
            for (int ni = 0; ni < 4; ++ni) oacc[mi][ni][r] *= alpha;
            lacc[mi][r] *= alpha;
          }
        }
        // P = exp2(s - m), truncate to bf16, write swizzled LDS
#pragma unroll
        for (int ni = 0; ni < 4; ++ni)
#pragma unroll
          for (int r = 0; r < 4; ++r) {
            float p = __builtin_amdgcn_exp2f(s[mi][ni][r] - m_run[mi][r]);
            int row = mi * 16 + lk * 4 + r;
            int colb = (ni * 16 + lr) * 2;
            Pw[row * 64 + ((colb ^ ((row & 7) << 4)) >> 1)] = f2b_trunc(p);
          }
      }

      // O += P @ V ; l += P @ ones (row-sum via MFMA, no shuffles)
      __builtin_amdgcn_s_setprio(1);
#pragma unroll
      for (int c = 0; c < 2; ++c) {
        const int cb = c * 64 + lk * 16;
        bf16x8 vf[4];
#pragma unroll
        for (int ni = 0; ni < 4; ++ni) {
          const int RV = ni * 16 + lr;
          vf[ni] = ldfrag(&Vs[buf][RV * 64 + ((cb ^ ((RV & 7) << 4)) >> 1)]);
        }
#pragma unroll
        for (int mi = 0; mi < 2; ++mi) {
          const int R = mi * 16 + lr;
          bf16x8 pf = ldfrag(&Pw[R * 64 + ((cb ^ ((R & 7) << 4)) >> 1)]);
          lacc[mi] = __builtin_amdgcn_mfma_f32_16x16x32_bf16(pf, ones, lacc[mi], 0, 0, 0);
#pragma unroll
          for (int ni = 0; ni < 4; ++ni)
            oacc[mi][ni] = __builtin_amdgcn_mfma_f32_16x16x32_bf16(pf, vf[ni], oacc[mi][ni], 0, 0, 0);
        }
      }
      __builtin_amdgcn_s_setprio(0);
    }
    __syncthreads();
    buf ^= 1;
  }

  const int b = bh >> 4, h = bh & 15;
#pragma unroll
  for (int mi = 0; mi < 2; ++mi) {
    float rl[4];
#pragma unroll
    for (int r = 0; r < 4; ++r) rl[r] = 1.0f / lacc[mi][r];
#pragma unroll
    for (int ni = 0; ni < 4; ++ni)
#pragma unroll
      for (int r = 0; r < 4; ++r) {
        float v = oacc[mi][ni][r] * rl[r];
        int n = wrow0 + mi * 16 + lk * 4 + r;
        Out[((size_t)(b * N + n)) * 1024 + h * 64 + ni * 16 + lr] = f2b(v);
      }
  }
}

// ---------- launch ----------
extern "C" void kernel_launch(void* const* d_in, const int* in_sizes, int n_in,
                              void* d_out, int out_size, void* d_ws, size_t ws_size,
                              hipStream_t stream) {
  const int B = 2, N = 2048, E = 1024, C = 1024, NC = 3072;
  const int M = B * N;  // 4096

  const float* x  = (const float*)d_in[0];
  const float* Wq = (const float*)d_in[1];
  const float* bq = (const float*)d_in[2];
  const float* Wk = (const float*)d_in[3];
  const float* bk = (const float*)d_in[4];
  const float* Wv = (const float*)d_in[5];
  const float* bv = (const float*)d_in[6];
  const float* Wo = (const float*)d_in[7];
  const float* bo = (const float*)d_in[8];

  char* w = (char*)d_ws;
  size_t off = 0;
  auto alloc = [&](size_t bytes) {
    void* p = w + off;
    off += (bytes + 255) & ~(size_t)255;
    return p;
  };
  unsigned short* xb    = (unsigned short*)alloc((size_t)M * E * 2);
  unsigned short* wqkv  = (unsigned short*)alloc((size_t)NC * E * 2);
  unsigned short* wob   = (unsigned short*)alloc((size_t)E * C * 2);
  unsigned short* qkvb  = (unsigned short*)alloc((size_t)M * NC * 2);
  unsigned short* qb    = (unsigned short*)alloc((size_t)B * 16 * N * 64 * 2);
  unsigned short* kb    = (unsigned short*)alloc((size_t)B * 16 * N * 64 * 2);
  unsigned short* vt    = (unsigned short*)alloc((size_t)B * 16 * 64 * N * 2);
  unsigned short* attnb = (unsigned short*)alloc((size_t)M * C * 2);
  float* sin_t   = (float*)alloc((size_t)N * 32 * 4);
  float* cos_t   = (float*)alloc((size_t)N * 32 * 4);
  float* biasqkv = (float*)alloc((size_t)NC * 4);

  hipMemcpyAsync(biasqkv,         bq, C * sizeof(float), hipMemcpyDeviceToDevice, stream);
  hipMemcpyAsync(biasqkv + C,     bk, C * sizeof(float), hipMemcpyDeviceToDevice, stream);
  hipMemcpyAsync(biasqkv + 2 * C, bv, C * sizeof(float), hipMemcpyDeviceToDevice, stream);

  int n1 = M * E / 4;
  cast_kernel<<<(n1 + 255) / 256, 256, 0, stream>>>(x, xb, n1);
  int n2 = C * E / 4;
  cast_kernel<<<(n2 + 255) / 256, 256, 0, stream>>>(Wq, wqkv, n2);
  cast_kernel<<<(n2 + 255) / 256, 256, 0, stream>>>(Wk, wqkv + (size_t)C * E, n2);
  cast_kernel<<<(n2 + 255) / 256, 256, 0, stream>>>(Wv, wqkv + (size_t)2 * C * E, n2);
  cast_kernel<<<(n2 + 255) / 256, 256, 0, stream>>>(Wo, wob, n2);

  int n3 = N * 32;
  sincos_kernel<<<(n3 + 255) / 256, 256, 0, stream>>>(sin_t, cos_t, n3);

  // QKV projection: [4096][1024] x [3072][1024]^T -> bf16 [4096][3072]
  gemm_bt<0><<<dim3(NC / 128, M / 128), 256, 0, stream>>>(xb, wqkv, qkvb, biasqkv, M, NC, E);

  // RoPE + layout to [bh][N][64]
  int nwaves = 2 * B * N * 16;
  rope_kernel<<<nwaves / 4, 256, 0, stream>>>(qkvb, sin_t, cos_t, qb, kb, N);

  // V transpose to [bh][64][N]
  vtrans_kernel<<<dim3(N / 64, B * 16), 256, 0, stream>>>(qkvb, vt, N);

  // causal flash attention: dual q-tile blocks, 512 threads, grid (8, 32)
  flash_kernel<<<dim3(8, B * 16), 512, 0, stream>>>(qb, kb, vt, attnb, N);

  // output projection: [4096][1024] x [1024][1024]^T + bo -> f32 d_out
  gemm_bt<1><<<dim3(E / 128, M / 128), 256, 0, stream>>>(attnb, wob, d_out, bo, M, E, C);
}

// Round 5
// 168.606 us; speedup vs baseline: 1.5708x; 1.1766x over previous
//
#include <hip/hip_runtime.h>
#include <hip/hip_bf16.h>
#include <cstdint>
#include <cstddef>

// ---------- types ----------
using bf16x8 = __attribute__((ext_vector_type(8))) __bf16;
using f32x4  = __attribute__((ext_vector_type(4))) float;

__device__ __forceinline__ float b2f(unsigned short u) {
  union { unsigned u; float f; } x; x.u = ((unsigned)u) << 16; return x.f;
}
__device__ __forceinline__ unsigned short f2b(float f) {
  union { float f; unsigned u; } x; x.f = f;
  unsigned r = x.u + 0x7fffu + ((x.u >> 16) & 1u);
  return (unsigned short)(r >> 16);
}
// truncating cast: safe for P because l is computed (via MFMA) from the SAME bf16 values.
__device__ __forceinline__ unsigned short f2b_trunc(float f) {
  union { float f; unsigned u; } x; x.f = f;
  return (unsigned short)(x.u >> 16);
}

// async global->LDS, 16B per lane. dst must be wave-uniform base (HW adds lane*16).
__device__ __forceinline__ void gload_lds16(const void* g, void* l) {
  __builtin_amdgcn_global_load_lds(
      (const __attribute__((address_space(1))) void*)g,
      (__attribute__((address_space(3))) void*)l, 16, 0, 0);
}

__device__ __forceinline__ bf16x8 ldfrag(const unsigned short* p) {
  return *reinterpret_cast<const bf16x8*>(p);
}

// ---------- prep kernels ----------
__global__ __launch_bounds__(256) void cast_kernel(const float* __restrict__ s,
                                                   unsigned short* __restrict__ d, int n4) {
  int i = blockIdx.x * 256 + threadIdx.x;
  if (i >= n4) return;
  float4 v = reinterpret_cast<const float4*>(s)[i];
  ushort4 o;
  o.x = f2b(v.x); o.y = f2b(v.y); o.z = f2b(v.z); o.w = f2b(v.w);
  reinterpret_cast<ushort4*>(d)[i] = o;
}

__global__ __launch_bounds__(256) void sincos_kernel(float* __restrict__ st,
                                                     float* __restrict__ ct, int total) {
  int i = blockIdx.x * 256 + threadIdx.x;
  if (i >= total) return;
  int n = i >> 5, j = i & 31;
  float inv = powf(10000.0f, -(float)j * (1.0f / 32.0f));
  float ang = (float)n * inv;
  st[i] = sinf(ang);
  ct[i] = cosf(ang);
}

// ---------- GEMM: C[M][N] = A[M][K] * B[N][K]^T (+bias), bf16 in, f32 acc ----------
template <int OUTF32>
__global__ __launch_bounds__(256) void gemm_bt(const unsigned short* __restrict__ A,
                                               const unsigned short* __restrict__ B,
                                               void* __restrict__ C,
                                               const float* __restrict__ bias,
                                               int M, int N, int K) {
  __shared__ __align__(16) unsigned short As[128 * 32];
  __shared__ __align__(16) unsigned short Bs[128 * 32];
  const int tid = threadIdx.x;
  const int lane = tid & 63, wave = tid >> 6;
  const int wr = wave >> 1, wc = wave & 1;
  const int bm = blockIdx.y * 128, bn = blockIdx.x * 128;
  const int lr = lane & 15, lk = lane >> 4;
  f32x4 acc[4][4] = {};

  for (int k0 = 0; k0 < K; k0 += 32) {
#pragma unroll
    for (int i = 0; i < 2; ++i) {
      int idx = i * 256 + tid;
      int row = idx >> 2, c8 = (idx & 3) * 8;
      gload_lds16(A + (size_t)(bm + row) * K + k0 + c8, &As[(i * 256 + wave * 64) * 8]);
      gload_lds16(B + (size_t)(bn + row) * K + k0 + c8, &Bs[(i * 256 + wave * 64) * 8]);
    }
    __syncthreads();
    bf16x8 af[4], bfr[4];
#pragma unroll
    for (int mi = 0; mi < 4; ++mi)
      af[mi] = ldfrag(&As[(wr * 64 + mi * 16 + lr) * 32 + lk * 8]);
#pragma unroll
    for (int ni = 0; ni < 4; ++ni)
      bfr[ni] = ldfrag(&Bs[(wc * 64 + ni * 16 + lr) * 32 + lk * 8]);
#pragma unroll
    for (int mi = 0; mi < 4; ++mi)
#pragma unroll
      for (int ni = 0; ni < 4; ++ni)
        acc[mi][ni] = __builtin_amdgcn_mfma_f32_16x16x32_bf16(af[mi], bfr[ni], acc[mi][ni], 0, 0, 0);
    __syncthreads();
  }

#pragma unroll
  for (int mi = 0; mi < 4; ++mi) {
#pragma unroll
    for (int ni = 0; ni < 4; ++ni) {
      int col = bn + wc * 64 + ni * 16 + lr;
      float bv = bias ? bias[col] : 0.0f;
#pragma unroll
      for (int r = 0; r < 4; ++r) {
        int row = bm + wr * 64 + mi * 16 + lk * 4 + r;
        float v = acc[mi][ni][r] + bv;
        if (OUTF32)
          reinterpret_cast<float*>(C)[(size_t)row * N + col] = v;
        else
          reinterpret_cast<unsigned short*>(C)[(size_t)row * N + col] = f2b(v);
      }
    }
  }
}

// ---------- RoPE: qkv[B*N][3072] -> Qo/Ko [B*16][N][64] ----------
// q pre-scaled by log2(e)/sqrt(D) so flash softmax runs in exp2 space.
__global__ __launch_bounds__(256) void rope_kernel(const unsigned short* __restrict__ qkv,
                                                   const float* __restrict__ st,
                                                   const float* __restrict__ ct,
                                                   unsigned short* __restrict__ Qo,
                                                   unsigned short* __restrict__ Ko, int N) {
  const int lane = threadIdx.x & 63;
  const int gw = (int)((blockIdx.x * 256 + threadIdx.x) >> 6);
  const int total = 2 * 2 * N * 16;
  if (gw >= total) return;
  const int which = gw / (2 * N * 16);  // 0=q, 1=k
  int rem = gw - which * (2 * N * 16);
  const int b = rem / (N * 16);
  rem -= b * (N * 16);
  const int n = rem >> 4, h = rem & 15;
  const int d = lane;
  float v = b2f(qkv[((size_t)(b * N + n)) * 3072 + which * 1024 + h * 64 + d]);
  const int j = d & 31;
  float c = ct[n * 32 + j], s = st[n * 32 + j];
  int partner = (d < 32) ? (2 * d + 1) : (2 * (d - 32));
  float pv = __shfl(v, partner, 64);
  float res = (d < 32) ? (v * c - pv * s) : (v * c + pv * s);
  if (which == 0) res *= 0.18033688f;  // (1/8) * log2(e)
  unsigned short* dst = which ? Ko : Qo;
  dst[(((size_t)(b * 16 + h)) * N + n) * 64 + d] = f2b(res);
}

// ---------- V transpose: qkv v-part [n][d] -> Vt[bh][d][n] ----------
__global__ __launch_bounds__(256) void vtrans_kernel(const unsigned short* __restrict__ qkv,
                                                     unsigned short* __restrict__ Vt, int N) {
  __shared__ __align__(16) unsigned short T[64][80];
  const int bh = blockIdx.y, b = bh >> 4, h = bh & 15;
  const int n0 = blockIdx.x * 64;
  const int tid = threadIdx.x;
#pragma unroll
  for (int i = 0; i < 2; ++i) {
    int idx = i * 256 + tid;
    int row = idx >> 3, c8 = (idx & 7) * 8;
    int4 v = *reinterpret_cast<const int4*>(
        &qkv[((size_t)(b * N + n0 + row)) * 3072 + 2048 + h * 64 + c8]);
    *reinterpret_cast<int4*>(&T[row][c8]) = v;
  }
  __syncthreads();
#pragma unroll
  for (int i = 0; i < 2; ++i) {
    int idx = i * 256 + tid;
    int d = idx >> 3, n8 = (idx & 7) * 8;
    int4 ov;
    ov.x = (int)T[n8 + 0][d] | ((int)T[n8 + 1][d] << 16);
    ov.y = (int)T[n8 + 2][d] | ((int)T[n8 + 3][d] << 16);
    ov.z = (int)T[n8 + 4][d] | ((int)T[n8 + 5][d] << 16);
    ov.w = (int)T[n8 + 6][d] | ((int)T[n8 + 7][d] << 16);
    *reinterpret_cast<int4*>(&Vt[((size_t)bh * 64 + d) * N + n0 + n8]) = ov;
  }
}

// ---------- Flash attention ----------
// Q/K [bh][N][64] (q pre-scaled, exp2 space), Vt [bh][64][N] -> Out bf16 [B][N][1024]
// 512 threads = 8 waves, 16 q-rows per wave = one 128-row q-tile per scan.
// Each block scans tile A (qt=x) then tile B (qt=15-x) SEQUENTIALLY over one
// shared K/V staging pipeline: (x+1) + (16-x) = 17 phases for EVERY block ->
// perfectly uniform work, all waves active every phase. KVBLK=128 halves the
// phase count per unit work. K/V double-buffered + XOR-swizzled; P per-wave.
// Dynamic LDS: 2*16K (K) + 2*16K (V) + 8*4K (P) = 96 KB.
__global__ __launch_bounds__(512) void flash_kernel(const unsigned short* __restrict__ Q,
                                                    const unsigned short* __restrict__ Kb,
                                                    const unsigned short* __restrict__ Vt,
                                                    unsigned short* __restrict__ Out, int N) {
  extern __shared__ __align__(16) unsigned short smem[];
  unsigned short* KsB = smem;           // [2][128*64]
  unsigned short* VsB = smem + 16384;   // [2][64*128]
  unsigned short* PsB = smem + 32768;   // [8][16*128]

  const int tid = threadIdx.x;
  const int lane = tid & 63, wave = tid >> 6;
  const int lr = lane & 15, lk = lane >> 4;
  const int bh = blockIdx.y;
  const int x = blockIdx.x;  // 0..7
  const int qtA = x, qtB = 15 - x;
  const int ntA = x + 1;     // + ntB = 17 phases total, uniform
  const unsigned short* Qh = Q + (size_t)bh * N * 64;
  const unsigned short* Kh = Kb + (size_t)bh * N * 64;
  const unsigned short* Vh = Vt + (size_t)bh * 64 * N;
  unsigned short* Pw = PsB + wave * 2048;

  const int wrowA = qtA * 128 + wave * 16;
  const int wrowB = qtB * 128 + wave * 16;

  // per-thread staging sources (pre-swizzled), advanced by constants per k-tile
  const int kr = tid >> 3;                                   // K row 0..63 (issue0)
  const int kcb = ((tid & 7) * 16) ^ ((kr & 7) << 4);
  const unsigned short* Kg0 = Kh + (size_t)kr * 64 + (kcb >> 1);
  const int vr = tid >> 4;                                   // V row 0..31 (issue0)
  const int vcb = ((tid & 15) * 16) ^ ((vr & 7) << 4);
  const unsigned short* Vg0 = Vh + (size_t)vr * N + (vcb >> 1);

  auto stage = [&](int buf, int tk) {
    const unsigned short* kp = Kg0 + (size_t)tk * 8192;      // tk*128 rows * 64
    const unsigned short* vp = Vg0 + (size_t)tk * 128;
    unsigned short* kl = KsB + buf * 8192 + wave * 512;
    unsigned short* vl = VsB + buf * 8192 + wave * 512;
    gload_lds16(kp, kl);
    gload_lds16(kp + 4096, kl + 4096);                       // +64 rows
    gload_lds16(vp, vl);
    gload_lds16(vp + (size_t)32 * N, vl + 4096);             // +32 rows
  };

  stage(0, 0);

  // Q fragments for both tiles (A-frag: row=lane&15, k-chunk=lk*8)
  bf16x8 qA0 = ldfrag(&Qh[(size_t)(wrowA + lr) * 64 + lk * 8]);
  bf16x8 qA1 = ldfrag(&Qh[(size_t)(wrowA + lr) * 64 + 32 + lk * 8]);
  bf16x8 qB0 = ldfrag(&Qh[(size_t)(wrowB + lr) * 64 + lk * 8]);
  bf16x8 qB1 = ldfrag(&Qh[(size_t)(wrowB + lr) * 64 + 32 + lk * 8]);

  bf16x8 ones;
  {
    union { unsigned short u; __bf16 b; } one; one.u = 0x3F80;
#pragma unroll
    for (int j = 0; j < 8; ++j) ones[j] = one.b;
  }

  f32x4 oacc[4] = {};
  f32x4 lacc = {};
  float m_run[4];
#pragma unroll
  for (int r = 0; r < 4; ++r) m_run[r] = -INFINITY;

  // one k-phase: QK^T (16 MFMA) -> online softmax -> P (LDS) -> PV + l-sum (20 MFMA)
  auto compute_phase = [&](int buf, bf16x8 q0, bf16x8 q1, bool diag) {
    const unsigned short* Ksb = KsB + buf * 8192;
    const unsigned short* Vsb = VsB + buf * 8192;
    f32x4 s[8];
#pragma unroll
    for (int ni = 0; ni < 8; ++ni) s[ni] = f32x4{0.f, 0.f, 0.f, 0.f};

    __builtin_amdgcn_s_setprio(1);
#pragma unroll
    for (int ni = 0; ni < 8; ++ni) {
      const int R = ni * 16 + lr;
      const int sw = (R & 7) << 4;
      bf16x8 kf0 = ldfrag(&Ksb[R * 64 + (((lk * 16) ^ sw) >> 1)]);
      bf16x8 kf1 = ldfrag(&Ksb[R * 64 + (((64 + lk * 16) ^ sw) >> 1)]);
      s[ni] = __builtin_amdgcn_mfma_f32_16x16x32_bf16(q0, kf0, s[ni], 0, 0, 0);
      s[ni] = __builtin_amdgcn_mfma_f32_16x16x32_bf16(q1, kf1, s[ni], 0, 0, 0);
    }
    __builtin_amdgcn_s_setprio(0);

    if (diag) {  // tile-local causal mask: col ni*16+lr vs row wave*16+lk*4+r
      const int qrow = wave * 16 + lk * 4;
#pragma unroll
      for (int ni = 0; ni < 8; ++ni)
#pragma unroll
        for (int r = 0; r < 4; ++r)
          if (ni * 16 + lr > qrow + r) s[ni][r] = -INFINITY;
    }

    // online softmax (exp2 space), defer-max THR=8
    float pmax[4];
    bool okl = true;
#pragma unroll
    for (int r = 0; r < 4; ++r) {
      float mx = s[0][r];
#pragma unroll
      for (int ni = 1; ni < 8; ++ni) mx = fmaxf(mx, s[ni][r]);
#pragma unroll
      for (int off = 1; off < 16; off <<= 1) mx = fmaxf(mx, __shfl_xor(mx, off, 64));
      pmax[r] = mx;
      okl = okl && (mx - m_run[r] <= 8.0f);
    }
    if (!__all(okl)) {
#pragma unroll
      for (int r = 0; r < 4; ++r) {
        float nm = fmaxf(m_run[r], pmax[r]);
        float alpha = __builtin_amdgcn_exp2f(m_run[r] - nm);
        m_run[r] = nm;
#pragma unroll
        for (int ni = 0; ni < 4; ++ni) oacc[ni][r] *= alpha;
        lacc[r] *= alpha;
      }
    }
    // P = exp2(s - m) -> bf16 (trunc) -> swizzled per-wave LDS [16][128]
#pragma unroll
    for (int ni = 0; ni < 8; ++ni)
#pragma unroll
      for (int r = 0; r < 4; ++r) {
        float p = __builtin_amdgcn_exp2f(s[ni][r] - m_run[r]);
        int row = lk * 4 + r;
        int colb = (ni * 16 + lr) * 2;
        Pw[row * 128 + ((colb ^ ((row & 7) << 4)) >> 1)] = f2b_trunc(p);
      }

    // O += P @ V ; l += P @ ones
    __builtin_amdgcn_s_setprio(1);
#pragma unroll
    for (int kc = 0; kc < 4; ++kc) {
      const int cb = kc * 64 + lk * 16;
      bf16x8 pf = ldfrag(&Pw[lr * 128 + ((cb ^ ((lr & 7) << 4)) >> 1)]);
      lacc = __builtin_amdgcn_mfma_f32_16x16x32_bf16(pf, ones, lacc, 0, 0, 0);
#pragma unroll
      for (int ni = 0; ni < 4; ++ni) {
        const int RV = ni * 16 + lr;
        bf16x8 vf = ldfrag(&Vsb[RV * 128 + ((cb ^ ((RV & 7) << 4)) >> 1)]);
        oacc[ni] = __builtin_amdgcn_mfma_f32_16x16x32_bf16(pf, vf, oacc[ni], 0, 0, 0);
      }
    }
    __builtin_amdgcn_s_setprio(0);
  };

  const int b = bh >> 4, h = bh & 15;
  auto epilogue = [&](int wrow0) {
    float rl[4];
#pragma unroll
    for (int r = 0; r < 4; ++r) rl[r] = 1.0f / lacc[r];
#pragma unroll
    for (int ni = 0; ni < 4; ++ni)
#pragma unroll
      for (int r = 0; r < 4; ++r) {
        float v = oacc[ni][r] * rl[r];
        int n = wrow0 + lk * 4 + r;
        Out[((size_t)(b * N + n)) * 1024 + h * 64 + ni * 16 + lr] = f2b(v);
      }
  };

  __syncthreads();

  int buf = 0;
  for (int p = 0; p < 17; ++p) {
    if (p + 1 < 17) {
      int tk2 = (p + 1 < ntA) ? (p + 1) : (p + 1 - ntA);
      stage(buf ^ 1, tk2);
    }
    if (p == ntA) {  // scan A done: write O_A, reset accumulators
      epilogue(wrowA);
#pragma unroll
      for (int ni = 0; ni < 4; ++ni) oacc[ni] = f32x4{0.f, 0.f, 0.f, 0.f};
      lacc = f32x4{0.f, 0.f, 0.f, 0.f};
#pragma unroll
      for (int r = 0; r < 4; ++r) m_run[r] = -INFINITY;
    }
    if (p < ntA) compute_phase(buf, qA0, qA1, p == ntA - 1);
    else         compute_phase(buf, qB0, qB1, p == 16);
    __syncthreads();
    buf ^= 1;
  }
  epilogue(wrowB);
}

// ---------- launch ----------
extern "C" void kernel_launch(void* const* d_in, const int* in_sizes, int n_in,
                              void* d_out, int out_size, void* d_ws, size_t ws_size,
                              hipStream_t stream) {
  const int B = 2, N = 2048, E = 1024, C = 1024, NC = 3072;
  const int M = B * N;  // 4096

  const float* x  = (const float*)d_in[0];
  const float* Wq = (const float*)d_in[1];
  const float* bq = (const float*)d_in[2];
  const float* Wk = (const float*)d_in[3];
  const float* bk = (const float*)d_in[4];
  const float* Wv = (const float*)d_in[5];
  const float* bv = (const float*)d_in[6];
  const float* Wo = (const float*)d_in[7];
  const float* bo = (const float*)d_in[8];

  char* w = (char*)d_ws;
  size_t off = 0;
  auto alloc = [&](size_t bytes) {
    void* p = w + off;
    off += (bytes + 255) & ~(size_t)255;
    return p;
  };
  unsigned short* xb    = (unsigned short*)alloc((size_t)M * E * 2);
  unsigned short* wqkv  = (unsigned short*)alloc((size_t)NC * E * 2);
  unsigned short* wob   = (unsigned short*)alloc((size_t)E * C * 2);
  unsigned short* qkvb  = (unsigned short*)alloc((size_t)M * NC * 2);
  unsigned short* qb    = (unsigned short*)alloc((size_t)B * 16 * N * 64 * 2);
  unsigned short* kb    = (unsigned short*)alloc((size_t)B * 16 * N * 64 * 2);
  unsigned short* vt    = (unsigned short*)alloc((size_t)B * 16 * 64 * N * 2);
  unsigned short* attnb = (unsigned short*)alloc((size_t)M * C * 2);
  float* sin_t   = (float*)alloc((size_t)N * 32 * 4);
  float* cos_t   = (float*)alloc((size_t)N * 32 * 4);
  float* biasqkv = (float*)alloc((size_t)NC * 4);

  hipMemcpyAsync(biasqkv,         bq, C * sizeof(float), hipMemcpyDeviceToDevice, stream);
  hipMemcpyAsync(biasqkv + C,     bk, C * sizeof(float), hipMemcpyDeviceToDevice, stream);
  hipMemcpyAsync(biasqkv + 2 * C, bv, C * sizeof(float), hipMemcpyDeviceToDevice, stream);

  int n1 = M * E / 4;
  cast_kernel<<<(n1 + 255) / 256, 256, 0, stream>>>(x, xb, n1);
  int n2 = C * E / 4;
  cast_kernel<<<(n2 + 255) / 256, 256, 0, stream>>>(Wq, wqkv, n2);
  cast_kernel<<<(n2 + 255) / 256, 256, 0, stream>>>(Wk, wqkv + (size_t)C * E, n2);
  cast_kernel<<<(n2 + 255) / 256, 256, 0, stream>>>(Wv, wqkv + (size_t)2 * C * E, n2);
  cast_kernel<<<(n2 + 255) / 256, 256, 0, stream>>>(Wo, wob, n2);

  int n3 = N * 32;
  sincos_kernel<<<(n3 + 255) / 256, 256, 0, stream>>>(sin_t, cos_t, n3);

  // QKV projection: [4096][1024] x [3072][1024]^T -> bf16 [4096][3072]
  gemm_bt<0><<<dim3(NC / 128, M / 128), 256, 0, stream>>>(xb, wqkv, qkvb, biasqkv, M, NC, E);

  // RoPE + layout to [bh][N][64]
  int nwaves = 2 * B * N * 16;
  rope_kernel<<<nwaves / 4, 256, 0, stream>>>(qkvb, sin_t, cos_t, qb, kb, N);

  // V transpose to [bh][64][N]
  vtrans_kernel<<<dim3(N / 64, B * 16), 256, 0, stream>>>(qkvb, vt, N);

  // causal flash attention: sequential dual-tile, 17 uniform phases, 96KB LDS
  static const int FLASH_LDS = 98304;
  hipFuncSetAttribute(reinterpret_cast<const void*>(flash_kernel),
                      hipFuncAttributeMaxDynamicSharedMemorySize, FLASH_LDS);
  flash_kernel<<<dim3(8, B * 16), 512, FLASH_LDS, stream>>>(qb, kb, vt, attnb, N);

  // output projection: [4096][1024] x [1024][1024]^T + bo -> f32 d_out
  gemm_bt<1><<<dim3(E / 128, M / 128), 256, 0, stream>>>(attnb, wob, d_out, bo, M, E, C);
}

// Round 7
// 151.747 us; speedup vs baseline: 1.7453x; 1.1111x over previous
//
#include <hip/hip_runtime.h>
#include <hip/hip_bf16.h>
#include <cstdint>
#include <cstddef>

// ---------- types ----------
using bf16x8 = __attribute__((ext_vector_type(8))) __bf16;
using f32x4  = __attribute__((ext_vector_type(4))) float;

__device__ __forceinline__ float b2f(unsigned short u) {
  union { unsigned u; float f; } x; x.u = ((unsigned)u) << 16; return x.f;
}
__device__ __forceinline__ unsigned short f2b(float f) {
  union { float f; unsigned u; } x; x.f = f;
  unsigned r = x.u + 0x7fffu + ((x.u >> 16) & 1u);
  return (unsigned short)(r >> 16);
}
// truncating cast: safe for P because l is computed (via MFMA) from the SAME bf16 values.
__device__ __forceinline__ unsigned short f2b_trunc(float f) {
  union { float f; unsigned u; } x; x.f = f;
  return (unsigned short)(x.u >> 16);
}

// async global->LDS, 16B per lane. dst must be wave-uniform base (HW adds lane*16).
__device__ __forceinline__ void gload_lds16(const void* g, void* l) {
  __builtin_amdgcn_global_load_lds(
      (const __attribute__((address_space(1))) void*)g,
      (__attribute__((address_space(3))) void*)l, 16, 0, 0);
}

__device__ __forceinline__ bf16x8 ldfrag(const unsigned short* p) {
  return *reinterpret_cast<const bf16x8*>(p);
}

// ---------- fused cast: x (1M float4), Wq/Wk/Wv/Wo (256K float4 each) -> bf16 ----------
__global__ __launch_bounds__(256) void cast_all_kernel(const float* __restrict__ x,
                                                       const float* __restrict__ Wq,
                                                       const float* __restrict__ Wk,
                                                       const float* __restrict__ Wv,
                                                       const float* __restrict__ Wo,
                                                       unsigned short* __restrict__ xb,
                                                       unsigned short* __restrict__ wqkv,
                                                       unsigned short* __restrict__ wob) {
  const int i = blockIdx.x * 256 + threadIdx.x;  // float4 index, total 2M
  const int XW = 1048576;                        // x: 4096*1024 floats = 1M float4
  const int WW = 262144;                         // each W: 1024*1024 floats = 256K float4
  const float* s; unsigned short* d; int j;
  if (i < XW)                { s = x;  d = xb;              j = i; }
  else if (i < XW + WW)      { s = Wq; d = wqkv;            j = i - XW; }
  else if (i < XW + 2 * WW)  { s = Wk; d = wqkv + 1048576;  j = i - XW - WW; }
  else if (i < XW + 3 * WW)  { s = Wv; d = wqkv + 2097152;  j = i - XW - 2 * WW; }
  else                       { s = Wo; d = wob;             j = i - XW - 3 * WW; }
  float4 v = reinterpret_cast<const float4*>(s)[j];
  ushort4 o;
  o.x = f2b(v.x); o.y = f2b(v.y); o.z = f2b(v.z); o.w = f2b(v.w);
  reinterpret_cast<ushort4*>(d)[j] = o;
}

__global__ __launch_bounds__(256) void sincos_kernel(float* __restrict__ st,
                                                     float* __restrict__ ct, int total) {
  int i = blockIdx.x * 256 + threadIdx.x;
  if (i >= total) return;
  int n = i >> 5, j = i & 31;
  float inv = powf(10000.0f, -(float)j * (1.0f / 32.0f));
  float ang = (float)n * inv;
  st[i] = sinf(ang);
  ct[i] = cosf(ang);
}

// ---------- 256x256 8-wave deep-pipelined GEMM (qkv projection) ----------
// C[M][N] = A[M][K]*B[N][K]^T + bias(q/k/v select), bf16 in/out.
// 512 thr = 8 waves (2Mx4N), per-wave 128x64 (acc[8][4]). BK=64, dbuf LDS 128KB.
// Per K-tile: burst-stage next tile (8 gload_lds), read b[4][2] once, then
// 4 phases {4 ds_read a-frags; s_barrier; setprio1; 16 MFMA; setprio0; s_barrier};
// single vmcnt(0)+barrier per K-tile (loads 4 phases old -> ~no stall).
// LDS swizzle byte^=(row&7)<<4 on stage-source AND reads (proven 0-conflict).
__global__ __launch_bounds__(512) void gemm256(const unsigned short* __restrict__ A,
                                               const unsigned short* __restrict__ B,
                                               unsigned short* __restrict__ C,
                                               const float* __restrict__ bq,
                                               const float* __restrict__ bk,
                                               const float* __restrict__ bv,
                                               int M, int N, int K, int TN) {
  extern __shared__ __align__(16) unsigned short sm[];  // [2][A 256x64 | B 256x64]
  const int tid = threadIdx.x, lane = tid & 63, wave = tid >> 6;
  const int lr = lane & 15, lk = lane >> 4;
  const int wr = wave >> 2, wc = wave & 3;  // 2 x 4 waves

  // XCD-bijective swizzle (grid % 8 == 0)
  int wg = (int)blockIdx.x;
  const int cpx = (int)gridDim.x >> 3;
  wg = (wg & 7) * cpx + (wg >> 3);
  const int bn = (wg % TN) * 256, bm = (wg / TN) * 256;

  // staging: thread t, issue i covers LDS half-rows; source pre-swizzled
  const int srow = wave * 8 + (lane >> 3);                       // + i*64 (+ h*128)
  const int scol = (((lane & 7) * 16) ^ (((lane >> 3) & 7) << 4)) >> 1;  // elems
  const unsigned short* Ag = A + (size_t)(bm + srow) * K + scol;
  const unsigned short* Bg = B + (size_t)(bn + srow) * K + scol;

  auto stage = [&](int kt, int nb) {
    const size_t ko = (size_t)kt * 64;
    unsigned short* base = sm + nb * 32768 + wave * 512;
#pragma unroll
    for (int h = 0; h < 2; ++h)
#pragma unroll
      for (int i = 0; i < 2; ++i) {
        const size_t ro = (size_t)(h * 128 + i * 64) * K + ko;
        gload_lds16(Ag + ro, base + h * 8192 + i * 4096);
        gload_lds16(Bg + ro, base + 16384 + h * 8192 + i * 4096);
      }
  };

  f32x4 acc[8][4] = {};
  const int swz = (lr & 7) << 4;  // row&7 == lr&7 for all frag rows
  const int NT = K / 64;

  stage(0, 0);
  asm volatile("s_waitcnt vmcnt(0)" ::: "memory");
  __builtin_amdgcn_s_barrier();

  for (int kt = 0; kt < NT; ++kt) {
    const int cur = kt & 1;
    if (kt + 1 < NT) stage(kt + 1, cur ^ 1);

    const unsigned short* Ab = sm + cur * 32768 + wr * 8192;
    const unsigned short* Bb = sm + cur * 32768 + 16384 + (wc >> 1) * 8192 + (wc & 1) * 4096;

    // b-frags once per K-tile: rows (wc&1)*64 + n*16 + lr, cols kk*64+lk*16 bytes
    bf16x8 b[4][2];
#pragma unroll
    for (int n = 0; n < 4; ++n)
#pragma unroll
      for (int kk = 0; kk < 2; ++kk)
        b[n][kk] = ldfrag(&Bb[(n * 16 + lr) * 64 + (((kk * 64 + lk * 16) ^ swz) >> 1)]);

#pragma unroll
    for (int q = 0; q < 4; ++q) {
      bf16x8 a[2][2];
#pragma unroll
      for (int m = 0; m < 2; ++m)
#pragma unroll
        for (int kk = 0; kk < 2; ++kk)
          a[m][kk] = ldfrag(&Ab[((q * 2 + m) * 16 + lr) * 64 + (((kk * 64 + lk * 16) ^ swz) >> 1)]);
      __builtin_amdgcn_s_barrier();
      __builtin_amdgcn_s_setprio(1);
#pragma unroll
      for (int kk = 0; kk < 2; ++kk)
#pragma unroll
        for (int m = 0; m < 2; ++m)
#pragma unroll
          for (int n = 0; n < 4; ++n)
            acc[q * 2 + m][n] =
                __builtin_amdgcn_mfma_f32_16x16x32_bf16(a[m][kk], b[n][kk], acc[q * 2 + m][n], 0, 0, 0);
      __builtin_amdgcn_s_setprio(0);
      if (q < 3) __builtin_amdgcn_s_barrier();
    }
    asm volatile("s_waitcnt vmcnt(0)" ::: "memory");
    __builtin_amdgcn_s_barrier();
  }

  // epilogue: bias select per 1024-col third
#pragma unroll
  for (int n = 0; n < 4; ++n) {
    const int col = bn + wc * 64 + n * 16 + lr;
    const int third = col >> 10, ci = col & 1023;
    const float bvv = (third == 0) ? bq[ci] : (third == 1) ? bk[ci] : bv[ci];
#pragma unroll
    for (int m = 0; m < 8; ++m)
#pragma unroll
      for (int r = 0; r < 4; ++r) {
        const int row = bm + wr * 128 + m * 16 + lk * 4 + r;
        C[(size_t)row * N + col] = f2b(acc[m][n][r] + bvv);
      }
  }
}

// ---------- GEMM: C[M][N] = A[M][K] * B[N][K]^T (+bias), bf16 in, f32 acc ----------
template <int OUTF32>
__global__ __launch_bounds__(256) void gemm_bt(const unsigned short* __restrict__ A,
                                               const unsigned short* __restrict__ B,
                                               void* __restrict__ C,
                                               const float* __restrict__ bias,
                                               int M, int N, int K) {
  __shared__ __align__(16) unsigned short As[128 * 32];
  __shared__ __align__(16) unsigned short Bs[128 * 32];
  const int tid = threadIdx.x;
  const int lane = tid & 63, wave = tid >> 6;
  const int wr = wave >> 1, wc = wave & 1;
  const int bm = blockIdx.y * 128, bn = blockIdx.x * 128;
  const int lr = lane & 15, lk = lane >> 4;
  f32x4 acc[4][4] = {};

  for (int k0 = 0; k0 < K; k0 += 32) {
#pragma unroll
    for (int i = 0; i < 2; ++i) {
      int idx = i * 256 + tid;
      int row = idx >> 2, c8 = (idx & 3) * 8;
      gload_lds16(A + (size_t)(bm + row) * K + k0 + c8, &As[(i * 256 + wave * 64) * 8]);
      gload_lds16(B + (size_t)(bn + row) * K + k0 + c8, &Bs[(i * 256 + wave * 64) * 8]);
    }
    __syncthreads();
    bf16x8 af[4], bfr[4];
#pragma unroll
    for (int mi = 0; mi < 4; ++mi)
      af[mi] = ldfrag(&As[(wr * 64 + mi * 16 + lr) * 32 + lk * 8]);
#pragma unroll
    for (int ni = 0; ni < 4; ++ni)
      bfr[ni] = ldfrag(&Bs[(wc * 64 + ni * 16 + lr) * 32 + lk * 8]);
#pragma unroll
    for (int mi = 0; mi < 4; ++mi)
#pragma unroll
      for (int ni = 0; ni < 4; ++ni)
        acc[mi][ni] = __builtin_amdgcn_mfma_f32_16x16x32_bf16(af[mi], bfr[ni], acc[mi][ni], 0, 0, 0);
    __syncthreads();
  }

#pragma unroll
  for (int mi = 0; mi < 4; ++mi) {
#pragma unroll
    for (int ni = 0; ni < 4; ++ni) {
      int col = bn + wc * 64 + ni * 16 + lr;
      float bv = bias ? bias[col] : 0.0f;
#pragma unroll
      for (int r = 0; r < 4; ++r) {
        int row = bm + wr * 64 + mi * 16 + lk * 4 + r;
        float v = acc[mi][ni][r] + bv;
        if (OUTF32)
          reinterpret_cast<float*>(C)[(size_t)row * N + col] = v;
        else
          reinterpret_cast<unsigned short*>(C)[(size_t)row * N + col] = f2b(v);
      }
    }
  }
}

// ---------- RoPE: qkv[B*N][3072] -> Qo/Ko [B*16][N][64] ----------
// q pre-scaled by log2(e)/sqrt(D) so flash softmax runs in exp2 space.
__global__ __launch_bounds__(256) void rope_kernel(const unsigned short* __restrict__ qkv,
                                                   const float* __restrict__ st,
                                                   const float* __restrict__ ct,
                                                   unsigned short* __restrict__ Qo,
                                                   unsigned short* __restrict__ Ko, int N) {
  const int lane = threadIdx.x & 63;
  const int gw = (int)((blockIdx.x * 256 + threadIdx.x) >> 6);
  const int total = 2 * 2 * N * 16;
  if (gw >= total) return;
  const int which = gw / (2 * N * 16);  // 0=q, 1=k
  int rem = gw - which * (2 * N * 16);
  const int b = rem / (N * 16);
  rem -= b * (N * 16);
  const int n = rem >> 4, h = rem & 15;
  const int d = lane;
  float v = b2f(qkv[((size_t)(b * N + n)) * 3072 + which * 1024 + h * 64 + d]);
  const int j = d & 31;
  float c = ct[n * 32 + j], s = st[n * 32 + j];
  int partner = (d < 32) ? (2 * d + 1) : (2 * (d - 32));
  float pv = __shfl(v, partner, 64);
  float res = (d < 32) ? (v * c - pv * s) : (v * c + pv * s);
  if (which == 0) res *= 0.18033688f;  // (1/8) * log2(e)
  unsigned short* dst = which ? Ko : Qo;
  dst[(((size_t)(b * 16 + h)) * N + n) * 64 + d] = f2b(res);
}

// ---------- V transpose: qkv v-part [n][d] -> Vt[bh][d][n] ----------
__global__ __launch_bounds__(256) void vtrans_kernel(const unsigned short* __restrict__ qkv,
                                                     unsigned short* __restrict__ Vt, int N) {
  __shared__ __align__(16) unsigned short T[64][80];
  const int bh = blockIdx.y, b = bh >> 4, h = bh & 15;
  const int n0 = blockIdx.x * 64;
  const int tid = threadIdx.x;
#pragma unroll
  for (int i = 0; i < 2; ++i) {
    int idx = i * 256 + tid;
    int row = idx >> 3, c8 = (idx & 7) * 8;
    int4 v = *reinterpret_cast<const int4*>(
        &qkv[((size_t)(b * N + n0 + row)) * 3072 + 2048 + h * 64 + c8]);
    *reinterpret_cast<int4*>(&T[row][c8]) = v;
  }
  __syncthreads();
#pragma unroll
  for (int i = 0; i < 2; ++i) {
    int idx = i * 256 + tid;
    int d = idx >> 3, n8 = (idx & 7) * 8;
    int4 ov;
    ov.x = (int)T[n8 + 0][d] | ((int)T[n8 + 1][d] << 16);
    ov.y = (int)T[n8 + 2][d] | ((int)T[n8 + 3][d] << 16);
    ov.z = (int)T[n8 + 4][d] | ((int)T[n8 + 5][d] << 16);
    ov.w = (int)T[n8 + 6][d] | ((int)T[n8 + 7][d] << 16);
    *reinterpret_cast<int4*>(&Vt[((size_t)bh * 64 + d) * N + n0 + n8]) = ov;
  }
}

// ---------- Flash attention (unchanged from R4) ----------
__global__ __launch_bounds__(512) void flash_kernel(const unsigned short* __restrict__ Q,
                                                    const unsigned short* __restrict__ Kb,
                                                    const unsigned short* __restrict__ Vt,
                                                    unsigned short* __restrict__ Out, int N) {
  extern __shared__ __align__(16) unsigned short smem[];
  unsigned short* KsB = smem;           // [2][128*64]
  unsigned short* VsB = smem + 16384;   // [2][64*128]
  unsigned short* PsB = smem + 32768;   // [8][16*128]

  const int tid = threadIdx.x;
  const int lane = tid & 63, wave = tid >> 6;
  const int lr = lane & 15, lk = lane >> 4;
  const int bh = blockIdx.y;
  const int x = blockIdx.x;  // 0..7
  const int qtA = x, qtB = 15 - x;
  const int ntA = x + 1;
  const unsigned short* Qh = Q + (size_t)bh * N * 64;
  const unsigned short* Kh = Kb + (size_t)bh * N * 64;
  const unsigned short* Vh = Vt + (size_t)bh * 64 * N;
  unsigned short* Pw = PsB + wave * 2048;

  const int wrowA = qtA * 128 + wave * 16;
  const int wrowB = qtB * 128 + wave * 16;

  const int kr = tid >> 3;
  const int kcb = ((tid & 7) * 16) ^ ((kr & 7) << 4);
  const unsigned short* Kg0 = Kh + (size_t)kr * 64 + (kcb >> 1);
  const int vr = tid >> 4;
  const int vcb = ((tid & 15) * 16) ^ ((vr & 7) << 4);
  const unsigned short* Vg0 = Vh + (size_t)vr * N + (vcb >> 1);

  auto stage = [&](int buf, int tk) {
    const unsigned short* kp = Kg0 + (size_t)tk * 8192;
    const unsigned short* vp = Vg0 + (size_t)tk * 128;
    unsigned short* kl = KsB + buf * 8192 + wave * 512;
    unsigned short* vl = VsB + buf * 8192 + wave * 512;
    gload_lds16(kp, kl);
    gload_lds16(kp + 4096, kl + 4096);
    gload_lds16(vp, vl);
    gload_lds16(vp + (size_t)32 * N, vl + 4096);
  };

  stage(0, 0);

  bf16x8 qA0 = ldfrag(&Qh[(size_t)(wrowA + lr) * 64 + lk * 8]);
  bf16x8 qA1 = ldfrag(&Qh[(size_t)(wrowA + lr) * 64 + 32 + lk * 8]);
  bf16x8 qB0 = ldfrag(&Qh[(size_t)(wrowB + lr) * 64 + lk * 8]);
  bf16x8 qB1 = ldfrag(&Qh[(size_t)(wrowB + lr) * 64 + 32 + lk * 8]);

  bf16x8 ones;
  {
    union { unsigned short u; __bf16 b; } one; one.u = 0x3F80;
#pragma unroll
    for (int j = 0; j < 8; ++j) ones[j] = one.b;
  }

  f32x4 oacc[4] = {};
  f32x4 lacc = {};
  float m_run[4];
#pragma unroll
  for (int r = 0; r < 4; ++r) m_run[r] = -INFINITY;

  auto compute_phase = [&](int buf, bf16x8 q0, bf16x8 q1, bool diag) {
    const unsigned short* Ksb = KsB + buf * 8192;
    const unsigned short* Vsb = VsB + buf * 8192;
    f32x4 s[8];
#pragma unroll
    for (int ni = 0; ni < 8; ++ni) s[ni] = f32x4{0.f, 0.f, 0.f, 0.f};

    __builtin_amdgcn_s_setprio(1);
#pragma unroll
    for (int ni = 0; ni < 8; ++ni) {
      const int R = ni * 16 + lr;
      const int sw = (R & 7) << 4;
      bf16x8 kf0 = ldfrag(&Ksb[R * 64 + (((lk * 16) ^ sw) >> 1)]);
      bf16x8 kf1 = ldfrag(&Ksb[R * 64 + (((64 + lk * 16) ^ sw) >> 1)]);
      s[ni] = __builtin_amdgcn_mfma_f32_16x16x32_bf16(q0, kf0, s[ni], 0, 0, 0);
      s[ni] = __builtin_amdgcn_mfma_f32_16x16x32_bf16(q1, kf1, s[ni], 0, 0, 0);
    }
    __builtin_amdgcn_s_setprio(0);

    if (diag) {
      const int qrow = wave * 16 + lk * 4;
#pragma unroll
      for (int ni = 0; ni < 8; ++ni)
#pragma unroll
        for (int r = 0; r < 4; ++r)
          if (ni * 16 + lr > qrow + r) s[ni][r] = -INFINITY;
    }

    float pmax[4];
    bool okl = true;
#pragma unroll
    for (int r = 0; r < 4; ++r) {
      float mx = s[0][r];
#pragma unroll
      for (int ni = 1; ni < 8; ++ni) mx = fmaxf(mx, s[ni][r]);
#pragma unroll
      for (int off = 1; off < 16; off <<= 1) mx = fmaxf(mx, __shfl_xor(mx, off, 64));
      pmax[r] = mx;
      okl = okl && (mx - m_run[r] <= 8.0f);
    }
    if (!__all(okl)) {
#pragma unroll
      for (int r = 0; r < 4; ++r) {
        float nm = fmaxf(m_run[r], pmax[r]);
        float alpha = __builtin_amdgcn_exp2f(m_run[r] - nm);
        m_run[r] = nm;
#pragma unroll
        for (int ni = 0; ni < 4; ++ni) oacc[ni][r] *= alpha;
        lacc[r] *= alpha;
      }
    }
#pragma unroll
    for (int ni = 0; ni < 8; ++ni)
#pragma unroll
      for (int r = 0; r < 4; ++r) {
        float p = __builtin_amdgcn_exp2f(s[ni][r] - m_run[r]);
        int row = lk * 4 + r;
        int colb = (ni * 16 + lr) * 2;
        Pw[row * 128 + ((colb ^ ((row & 7) << 4)) >> 1)] = f2b_trunc(p);
      }

    __builtin_amdgcn_s_setprio(1);
#pragma unroll
    for (int kc = 0; kc < 4; ++kc) {
      const int cb = kc * 64 + lk * 16;
      bf16x8 pf = ldfrag(&Pw[lr * 128 + ((cb ^ ((lr & 7) << 4)) >> 1)]);
      lacc = __builtin_amdgcn_mfma_f32_16x16x32_bf16(pf, ones, lacc, 0, 0, 0);
#pragma unroll
      for (int ni = 0; ni < 4; ++ni) {
        const int RV = ni * 16 + lr;
        bf16x8 vf = ldfrag(&Vsb[RV * 128 + ((cb ^ ((RV & 7) << 4)) >> 1)]);
        oacc[ni] = __builtin_amdgcn_mfma_f32_16x16x32_bf16(pf, vf, oacc[ni], 0, 0, 0);
      }
    }
    __builtin_amdgcn_s_setprio(0);
  };

  const int b = bh >> 4, h = bh & 15;
  auto epilogue = [&](int wrow0) {
    float rl[4];
#pragma unroll
    for (int r = 0; r < 4; ++r) rl[r] = 1.0f / lacc[r];
#pragma unroll
    for (int ni = 0; ni < 4; ++ni)
#pragma unroll
      for (int r = 0; r < 4; ++r) {
        float v = oacc[ni][r] * rl[r];
        int n = wrow0 + lk * 4 + r;
        Out[((size_t)(b * N + n)) * 1024 + h * 64 + ni * 16 + lr] = f2b(v);
      }
  };

  __syncthreads();

  int buf = 0;
  for (int p = 0; p < 17; ++p) {
    if (p + 1 < 17) {
      int tk2 = (p + 1 < ntA) ? (p + 1) : (p + 1 - ntA);
      stage(buf ^ 1, tk2);
    }
    if (p == ntA) {
      epilogue(wrowA);
#pragma unroll
      for (int ni = 0; ni < 4; ++ni) oacc[ni] = f32x4{0.f, 0.f, 0.f, 0.f};
      lacc = f32x4{0.f, 0.f, 0.f, 0.f};
#pragma unroll
      for (int r = 0; r < 4; ++r) m_run[r] = -INFINITY;
    }
    if (p < ntA) compute_phase(buf, qA0, qA1, p == ntA - 1);
    else         compute_phase(buf, qB0, qB1, p == 16);
    __syncthreads();
    buf ^= 1;
  }
  epilogue(wrowB);
}

// ---------- launch ----------
extern "C" void kernel_launch(void* const* d_in, const int* in_sizes, int n_in,
                              void* d_out, int out_size, void* d_ws, size_t ws_size,
                              hipStream_t stream) {
  const int B = 2, N = 2048, E = 1024, C = 1024, NC = 3072;
  const int M = B * N;  // 4096

  const float* x  = (const float*)d_in[0];
  const float* Wq = (const float*)d_in[1];
  const float* bq = (const float*)d_in[2];
  const float* Wk = (const float*)d_in[3];
  const float* bk = (const float*)d_in[4];
  const float* Wv = (const float*)d_in[5];
  const float* bv = (const float*)d_in[6];
  const float* Wo = (const float*)d_in[7];
  const float* bo = (const float*)d_in[8];

  char* w = (char*)d_ws;
  size_t off = 0;
  auto alloc = [&](size_t bytes) {
    void* p = w + off;
    off += (bytes + 255) & ~(size_t)255;
    return p;
  };
  unsigned short* xb    = (unsigned short*)alloc((size_t)M * E * 2);
  unsigned short* wqkv  = (unsigned short*)alloc((size_t)NC * E * 2);
  unsigned short* wob   = (unsigned short*)alloc((size_t)E * C * 2);
  unsigned short* qkvb  = (unsigned short*)alloc((size_t)M * NC * 2);
  unsigned short* qb    = (unsigned short*)alloc((size_t)B * 16 * N * 64 * 2);
  unsigned short* kb    = (unsigned short*)alloc((size_t)B * 16 * N * 64 * 2);
  unsigned short* vt    = (unsigned short*)alloc((size_t)B * 16 * 64 * N * 2);
  unsigned short* attnb = (unsigned short*)alloc((size_t)M * C * 2);
  float* sin_t = (float*)alloc((size_t)N * 32 * 4);
  float* cos_t = (float*)alloc((size_t)N * 32 * 4);

  // fused bf16 casts (x, Wq, Wk, Wv, Wo) — one kernel, 2M float4 total
  cast_all_kernel<<<8192, 256, 0, stream>>>(x, Wq, Wk, Wv, Wo, xb, wqkv, wob);

  int n3 = N * 32;
  sincos_kernel<<<(n3 + 255) / 256, 256, 0, stream>>>(sin_t, cos_t, n3);

  // QKV projection: 256^2 deep-pipelined GEMM, bias select in epilogue
  static const int GEMM_LDS = 131072;
  hipFuncSetAttribute(reinterpret_cast<const void*>(gemm256),
                      hipFuncAttributeMaxDynamicSharedMemorySize, GEMM_LDS);
  gemm256<<<dim3((NC / 256) * (M / 256)), 512, GEMM_LDS, stream>>>(
      xb, wqkv, qkvb, bq, bk, bv, M, NC, E, NC / 256);

  // RoPE + layout to [bh][N][64]
  int nwaves = 2 * B * N * 16;
  rope_kernel<<<nwaves / 4, 256, 0, stream>>>(qkvb, sin_t, cos_t, qb, kb, N);

  // V transpose to [bh][64][N]
  vtrans_kernel<<<dim3(N / 64, B * 16), 256, 0, stream>>>(qkvb, vt, N);

  // causal flash attention: sequential dual-tile, 17 uniform phases, 96KB LDS
  static const int FLASH_LDS = 98304;
  hipFuncSetAttribute(reinterpret_cast<const void*>(flash_kernel),
                      hipFuncAttributeMaxDynamicSharedMemorySize, FLASH_LDS);
  flash_kernel<<<dim3(8, B * 16), 512, FLASH_LDS, stream>>>(qb, kb, vt, attnb, N);

  // output projection: [4096][1024] x [1024][1024]^T + bo -> f32 d_out
  gemm_bt<1><<<dim3(E / 128, M / 128), 256, 0, stream>>>(attnb, wob, d_out, bo, M, E, C);
}